// Round 7
// baseline (383.931 us; speedup 1.0000x reference)
//
#include <hip/hip_runtime.h>
#include <hip/hip_bf16.h>

// Match numpy: no FMA contraction anywhere that feeds the Jacobi pivots.
#pragma clang fp contract(off)

#define N 4096
#define CIN 64
#define COUT 64
#define ITERS 10
#define MAXS 40

typedef unsigned long long u64;

// pack (|value|, col j): bigger value wins; tie -> smaller j
__device__ __forceinline__ u64 packkey(float v, unsigned j) {
    return ((u64)__float_as_uint(v) << 32) | (u64)(~j);
}

// ---------- setup ----------
__global__ void init_k(int* __restrict__ deg, int* __restrict__ fill,
                       int* __restrict__ dslot) {
    int i = blockIdx.x * 256 + threadIdx.x;
    if (i < N) { deg[i] = 0; fill[i] = 0; dslot[i] = -1; }
}

__global__ void edges1_k(const int* __restrict__ ei, int* __restrict__ deg, int E) {
    int e = blockIdx.x * 256 + threadIdx.x;
    if (e < E) atomicAdd(&deg[ei[e]], 1);
}

__global__ void __launch_bounds__(1024) scan_k(const int* __restrict__ deg,
                                               int* __restrict__ rowptr,
                                               float* __restrict__ dinv) {
    __shared__ int ps[1024];
    int t = threadIdx.x, b = t * 4;
    int d0 = deg[b], d1 = deg[b + 1], d2 = deg[b + 2], d3 = deg[b + 3];
    int local = d0 + d1 + d2 + d3;
    ps[t] = local;
    __syncthreads();
    for (int off = 1; off < 1024; off <<= 1) {
        int v = (t >= off) ? ps[t - off] : 0;
        __syncthreads();
        ps[t] += v;
        __syncthreads();
    }
    int excl = ps[t] - local;
    rowptr[b] = excl; rowptr[b + 1] = excl + d0;
    rowptr[b + 2] = excl + d0 + d1; rowptr[b + 3] = excl + d0 + d1 + d2;
    if (t == 1023) rowptr[4096] = ps[1023];
    dinv[b]     = d0 > 0 ? 1.0f / sqrtf((float)d0) : 0.0f;
    dinv[b + 1] = d1 > 0 ? 1.0f / sqrtf((float)d1) : 0.0f;
    dinv[b + 2] = d2 > 0 ? 1.0f / sqrtf((float)d2) : 0.0f;
    dinv[b + 3] = d3 > 0 ? 1.0f / sqrtf((float)d3) : 0.0f;
}

__global__ void edges2_k(const int* __restrict__ ei, const int* __restrict__ rowptr,
                         int* __restrict__ fill, int* __restrict__ colidx, int E) {
    int e = blockIdx.x * 256 + threadIdx.x;
    if (e < E) {
        int r = ei[e], c = ei[E + e];
        int pos = rowptr[r] + atomicAdd(&fill[r], 1);
        colidx[pos] = c;
    }
}

__global__ void prepw_k(const float* __restrict__ hh, const float* __restrict__ cw,
                        const float* __restrict__ rw, const float* __restrict__ iw,
                        float2* __restrict__ hcT, float4* __restrict__ rwT,
                        float4* __restrict__ iwT) {
    int idx = blockIdx.x * 256 + threadIdx.x;
    int i = idx >> 6, o = idx & 63;
    int src = o * 64 + i;
    hcT[idx] = make_float2(hh[src], cw[src]);
    rwT[idx] = make_float4(rw[src * 4 + 0], rw[src * 4 + 1], rw[src * 4 + 2], rw[src * 4 + 3]);
    iwT[idx] = make_float4(iw[src * 4 + 0], iw[src * 4 + 1], iw[src * 4 + 2], iw[src * 4 + 3]);
}

// per-row max of |L_ij| (j>i), diag, and y=x copy. One block per row.
__global__ void __launch_bounds__(256) rowmax0_k(
        const int* __restrict__ rowptr, const int* __restrict__ colidx,
        const float* __restrict__ dinv, const float* __restrict__ x,
        float* __restrict__ y, float* __restrict__ diag,
        u64* __restrict__ rowmax, float* __restrict__ rowval) {
    const int i = blockIdx.x, t = threadIdx.x;
    __shared__ float row[N];
    __shared__ u64 w4[4];
    for (int j = t; j < N; j += 256) row[j] = 0.0f;
    __syncthreads();
    for (int e = rowptr[i] + t; e < rowptr[i + 1]; e += 256)
        atomicAdd(&row[colidx[e]], 1.0f);
    __syncthreads();
    float di = dinv[i];
    u64 best = packkey(0.0f, 4095u);
    for (int j = t; j < N; j += 256) {
        if (j > i) {
            float v = -((di * row[j]) * dinv[j]);
            u64 kk = packkey(fabsf(v), (unsigned)j);
            if (kk > best) best = kk;
        }
    }
    for (int off = 32; off; off >>= 1) { u64 o = __shfl_down(best, off, 64); if (o > best) best = o; }
    if ((t & 63) == 0) w4[t >> 6] = best;
    __syncthreads();
    if (t == 0) {
        u64 b = w4[0];
        for (int w = 1; w < 4; ++w) if (w4[w] > b) b = w4[w];
        unsigned js = (~(unsigned)b) & 4095u;
        rowmax[i] = b;
        rowval[i] = -((di * row[js]) * dinv[js]);
        diag[i] = 1.0f - ((di * row[i]) * di);
    }
    if (t < CIN) y[i * CIN + t] = x[i * CIN + t];
}

// ---------- persistent single-block Jacobi: all ITERS iterations ----------
__global__ void __launch_bounds__(1024) jacobi_k(
        const int* __restrict__ rowptr, const int* __restrict__ colidx,
        const float* __restrict__ dinv,
        float* __restrict__ diag, const u64* __restrict__ rowmaxG,
        const float* __restrict__ rowvalG, float* __restrict__ y,
        float* __restrict__ rowS, float* __restrict__ colS,
        int* __restrict__ dslot, int* __restrict__ slistG, int* __restrict__ nslotsG,
        int* __restrict__ rotk, int* __restrict__ rotl,
        float* __restrict__ rotc, float* __restrict__ rotsv) {
    __shared__ float bufK[N], bufL[N];     // 32 KB
    __shared__ u64 rmaxL[N];               // 32 KB
    __shared__ float rvalL[N];             // 16 KB
    __shared__ float rowscr[N];            // 16 KB
    __shared__ int sdirty[N];              // 16 KB
    __shared__ u64 w16[16], w16b[16];
    __shared__ float sRowK[MAXS], sRowL[MAXS];
    __shared__ int slistL[MAXS];
    __shared__ int S_k, S_l, S_slotk, S_slotl, S_oldk, S_oldl, S_nold, S_ns, S_snd;
    __shared__ float S_c, S_s, S_a2kk, S_a2ll;
    const int t = threadIdx.x;

    for (int i = t; i < N; i += 1024) { rmaxL[i] = rowmaxG[i]; rvalL[i] = rowvalG[i]; }
    if (t == 0) S_ns = 0;
    __syncthreads();

    for (int it = 0; it < ITERS; ++it) {
        // ---- P0: pivot select (val desc, flat idx asc = np.argmax row-major) ----
        u64 best = 0ull;
        for (int r = t; r < N; r += 1024) {
            u64 p = rmaxL[r];
            unsigned vb = (unsigned)(p >> 32);
            unsigned j = (~(unsigned)p) & 4095u;
            unsigned flat = ((unsigned)r << 12) | j;
            u64 key = ((u64)vb << 24) | (u64)((~flat) & 0xFFFFFFu);
            if (key > best) best = key;
        }
        for (int off = 32; off; off >>= 1) { u64 o = __shfl_down(best, off, 64); if (o > best) best = o; }
        if ((t & 63) == 0) w16[t >> 6] = best;
        __syncthreads();
        if (t == 0) {
            u64 b = w16[0];
            for (int w = 1; w < 16; ++w) if (w16[w] > b) b = w16[w];
            unsigned flat = (~(unsigned)b) & 0xFFFFFFu;
            int k = (int)(flat >> 12), l = (int)(flat & 4095u);
            float akl = rvalL[k];
            float akk = diag[k], all_ = diag[l];
            float aDiff = all_ - akk;
            float akl_safe = (akl == 0.0f) ? 1.0f : akl;
            float aDiff_safe = (aDiff == 0.0f) ? 1.0f : aDiff;
            float phi = aDiff / (2.0f * akl_safe);
            float t2 = 1.0f / (fabsf(phi) + sqrtf(phi * phi + 1.0f));
            t2 = (phi < 0.0f) ? -t2 : t2;
            float t1 = akl / aDiff_safe;
            float tt = (fabsf(akl) < fabsf(aDiff) * 1e-36f) ? t1 : t2;
            float cv = 1.0f / sqrtf(tt * tt + 1.0f);
            float sv = tt * cv;
            rotk[it] = k; rotl[it] = l; rotc[it] = cv; rotsv[it] = sv;
            int ns = S_ns;
            S_nold = ns;
            int ok = dslot[k]; S_oldk = ok;
            int sk = ok; if (ok < 0) { sk = ns; slistL[ns] = k; dslot[k] = ns; ns++; }
            int ol = dslot[l]; S_oldl = ol;
            int sl = ol; if (ol < 0) { sl = ns; slistL[ns] = l; dslot[l] = ns; ns++; }
            S_ns = ns;
            S_k = k; S_l = l; S_slotk = sk; S_slotl = sl; S_c = cv; S_s = sv;
        }
        __syncthreads();
        const int k = S_k, l = S_l, slotk = S_slotk, slotl = S_slotl;
        const int oldk = S_oldk, oldl = S_oldl, nold = S_nold;
        const float c = S_c, s = S_s;
        // ---- P1: incremental U^T x ----
        if (t < CIN) {
            float yk = y[k * CIN + t], yl = y[l * CIN + t];
            y[k * CIN + t] = c * yk - s * yl;
            y[l * CIN + t] = s * yk + c * yl;
        }
        const float dk = dinv[k], dl = dinv[l];

        // ---- P2: build rows k,l (reference orientation a_kj / a_lj) ----
        for (int j = t; j < N; j += 1024) { bufK[j] = 0.0f; bufL[j] = 0.0f; }
        __syncthreads();
        if (oldk < 0) for (int e = rowptr[k] + t; e < rowptr[k + 1]; e += 1024) atomicAdd(&bufK[colidx[e]], 1.0f);
        if (oldl < 0) for (int e = rowptr[l] + t; e < rowptr[l + 1]; e += 1024) atomicAdd(&bufL[colidx[e]], 1.0f);
        __syncthreads();
        for (int j = t; j < N; j += 1024) {
            float vk = (oldk >= 0) ? rowS[(size_t)oldk * N + j] : -((dk * bufK[j]) * dinv[j]);
            float vl = (oldl >= 0) ? rowS[(size_t)oldl * N + j] : -((dl * bufL[j]) * dinv[j]);
            bufK[j] = vk; bufL[j] = vl;
        }
        __syncthreads();
        if (t < nold) {   // overlay prior-pivot columns for fresh rows
            int js = slistL[t];
            if (oldk < 0) bufK[js] = colS[(size_t)t * N + k];
            if (oldl < 0) bufL[js] = colS[(size_t)t * N + l];
        }
        __syncthreads();
        if (t == 0) {     // 2x2 block, exact reference op order
            bufK[k] = diag[k]; bufL[l] = diag[l];
            float akk = bufK[k], all_ = bufL[l], akl = bufK[l], alk = bufL[k];
            float a1kk = c * akk - s * akl;
            float a1kl = s * akk + c * akl;
            float a1lk = c * alk - s * all_;
            float a1ll = s * alk + c * all_;
            S_a2kk = c * a1kk - s * a1lk;
            S_a2ll = s * a1kl + c * a1ll;
            diag[k] = S_a2kk; diag[l] = S_a2ll;
        }
        __syncthreads();
        const float a2kk = S_a2kk, a2ll = S_a2ll;
        // ---- P3: rotate rows in place, write rowS, rowmax for k,l ----
        u64 bk = packkey(0.0f, 4095u), bl = packkey(0.0f, 4095u);
        for (int j = t; j < N; j += 1024) {
            float rk = bufK[j], rl = bufL[j], nk, nl;
            if (j == k)      { nk = a2kk; nl = 0.0f; }
            else if (j == l) { nk = 0.0f; nl = a2ll; }
            else             { nk = c * rk - s * rl; nl = s * rk + c * rl; }
            bufK[j] = nk; bufL[j] = nl;
            rowS[(size_t)slotk * N + j] = nk;
            rowS[(size_t)slotl * N + j] = nl;
            if (j > k) { u64 kk = packkey(fabsf(nk), (unsigned)j); if (kk > bk) bk = kk; }
            if (j > l) { u64 kk = packkey(fabsf(nl), (unsigned)j); if (kk > bl) bl = kk; }
        }
        __syncthreads();
        if (t < nold) {   // capture new-row values at old-pivot columns (post-rotation)
            int js = slistL[t];
            sRowK[t] = bufK[js];
            sRowL[t] = bufL[js];
        }
        for (int off = 32; off; off >>= 1) {
            u64 o = __shfl_down(bk, off, 64); if (o > bk) bk = o;
            u64 o2 = __shfl_down(bl, off, 64); if (o2 > bl) bl = o2;
        }
        if ((t & 63) == 0) { w16[t >> 6] = bk; w16b[t >> 6] = bl; }
        __syncthreads();
        if (t == 0) {
            u64 b1 = w16[0], b2 = w16b[0];
            for (int w = 1; w < 16; ++w) { if (w16[w] > b1) b1 = w16[w]; if (w16b[w] > b2) b2 = w16b[w]; }
            unsigned j1 = (~(unsigned)b1) & 4095u, j2 = (~(unsigned)b2) & 4095u;
            rmaxL[k] = b1; rvalL[k] = bufK[j1];
            rmaxL[l] = b2; rvalL[l] = bufL[j2];
        }
        __syncthreads();
        // ---- P4: build+rotate columns k,l (reference orientation a_jk / a_jl) ----
        for (int j = t; j < N; j += 1024) { bufK[j] = 0.0f; bufL[j] = 0.0f; }
        __syncthreads();
        if (oldk < 0) for (int e = rowptr[k] + t; e < rowptr[k + 1]; e += 1024) atomicAdd(&bufK[colidx[e]], 1.0f);
        if (oldl < 0) for (int e = rowptr[l] + t; e < rowptr[l + 1]; e += 1024) atomicAdd(&bufL[colidx[e]], 1.0f);
        __syncthreads();
        for (int j = t; j < N; j += 1024) {
            float vk = (oldk >= 0) ? colS[(size_t)oldk * N + j] : -((dinv[j] * bufK[j]) * dk);
            float vl = (oldl >= 0) ? colS[(size_t)oldl * N + j] : -((dinv[j] * bufL[j]) * dl);
            bufK[j] = vk; bufL[j] = vl;
        }
        __syncthreads();
        if (t < nold) {   // overlay prior-pivot rows for fresh columns
            int js = slistL[t];
            if (js != k && js != l) {
                if (oldk < 0) bufK[js] = rowS[(size_t)t * N + k];
                if (oldl < 0) bufL[js] = rowS[(size_t)t * N + l];
            }
        }
        __syncthreads();
        for (int j = t; j < N; j += 1024) {
            float ck_ = bufK[j], cl_ = bufL[j], nk, nl;
            if (j == k)      { nk = a2kk; nl = 0.0f; }
            else if (j == l) { nk = 0.0f; nl = a2ll; }
            else             { nk = c * ck_ - s * cl_; nl = s * ck_ + c * cl_; }
            colS[(size_t)slotk * N + j] = nk;
            colS[(size_t)slotl * N + j] = nl;
            bufK[j] = nk; bufL[j] = nl;   // keep rotated columns in LDS for merge
        }
        __syncthreads();
        // ---- P5: patch all old slots at rows/cols k,l ----
        if (t < nold) {
            int js = slistL[t];
            if (js != k && js != l) {
                colS[(size_t)t * N + k] = sRowK[t];     // new a_{k,js}
                colS[(size_t)t * N + l] = sRowL[t];     // new a_{l,js}
                rowS[(size_t)t * N + k] = bufK[js];     // new a_{js,k}
                rowS[(size_t)t * N + l] = bufL[js];     // new a_{js,l}
            }
        }
        if (t == 0) S_snd = 0;
        __syncthreads();
        // ---- P6: merge rowmax for all other rows ----
        for (int i = t; i < N; i += 1024) {
            if (i == k || i == l) continue;
            float nik = bufK[i];          // new a_{i,k}
            float nil = bufL[i];          // new a_{i,l}
            u64 cached = rmaxL[i];
            unsigned cj = (~(unsigned)cached) & 4095u;
            bool kc = (k > i), lc = (l > i);
            u64 ck_ = kc ? packkey(fabsf(nik), (unsigned)k) : 0ull;
            u64 cl_ = lc ? packkey(fabsf(nil), (unsigned)l) : 0ull;
            bool stale = false; u64 base = cached; bool useOld = true;
            if (kc && cj == (unsigned)k)      { if (ck_ < cached) stale = true; else { base = 0ull; useOld = false; } }
            else if (lc && cj == (unsigned)l) { if (cl_ < cached) stale = true; else { base = 0ull; useOld = false; } }
            if (!stale) {
                if (kc || lc) {
                    u64 m = base; float mv = useOld ? rvalL[i] : 0.0f;
                    if (ck_ > m) { m = ck_; mv = nik; }
                    if (cl_ > m) { m = cl_; mv = nil; }
                    rmaxL[i] = m; rvalL[i] = mv;
                }
            } else {
                int d = atomicAdd(&S_snd, 1);
                sdirty[d] = i;
            }
        }
        __syncthreads();
        const int nd = S_snd;
        const int ns2 = S_ns;
        for (int d = 0; d < nd; ++d) {
            int ir = sdirty[d];
            int slot = dslot[ir];          // block-uniform global read
            u64 bb = packkey(0.0f, 4095u);
            if (slot >= 0) {               // former pivot: dense row stored & patched
                for (int j = t; j < N; j += 1024) {
                    if (j > ir) {
                        float v = rowS[(size_t)slot * N + j];
                        u64 kk = packkey(fabsf(v), (unsigned)j);
                        if (kk > bb) bb = kk;
                    }
                }
                for (int off = 32; off; off >>= 1) { u64 o = __shfl_down(bb, off, 64); if (o > bb) bb = o; }
                if ((t & 63) == 0) w16[t >> 6] = bb;
                __syncthreads();
                if (t == 0) {
                    u64 b = w16[0];
                    for (int w = 1; w < 16; ++w) if (w16[w] > b) b = w16[w];
                    unsigned js = (~(unsigned)b) & 4095u;
                    rmaxL[ir] = b; rvalL[ir] = rowS[(size_t)slot * N + js];
                }
                __syncthreads();
            } else {                        // rebuild row ir from CSR + slot overlays
                for (int j = t; j < N; j += 1024) rowscr[j] = 0.0f;
                __syncthreads();
                for (int e = rowptr[ir] + t; e < rowptr[ir + 1]; e += 1024)
                    atomicAdd(&rowscr[colidx[e]], 1.0f);
                __syncthreads();
                float di = dinv[ir];
                for (int j = t; j < N; j += 1024) rowscr[j] = -((di * rowscr[j]) * dinv[j]);
                __syncthreads();
                if (t < ns2) {
                    int js = slistL[t];
                    if (js != ir) {
                        float v = (t == slotk) ? bufK[ir] : (t == slotl) ? bufL[ir]
                                  : colS[(size_t)t * N + ir];
                        rowscr[js] = v;
                    }
                }
                __syncthreads();
                for (int j = t; j < N; j += 1024) {
                    if (j > ir) { u64 kk = packkey(fabsf(rowscr[j]), (unsigned)j); if (kk > bb) bb = kk; }
                }
                for (int off = 32; off; off >>= 1) { u64 o = __shfl_down(bb, off, 64); if (o > bb) bb = o; }
                if ((t & 63) == 0) w16[t >> 6] = bb;
                __syncthreads();
                if (t == 0) {
                    u64 b = w16[0];
                    for (int w = 1; w < 16; ++w) if (w16[w] > b) b = w16[w];
                    unsigned js = (~(unsigned)b) & 4095u;
                    rmaxL[ir] = b; rvalL[ir] = rowscr[js];
                }
                __syncthreads();
            }
        }
        __syncthreads();
    }
    // mirror slot list for the store kernel
    if (t < S_ns) slistG[t] = slistL[t];
    if (t == 0) *nslotsG = S_ns;
}

// ---------- tail ----------
__global__ void __launch_bounds__(1024) spectral_k(
        const float* __restrict__ diag, const float* __restrict__ y,
        const float2* __restrict__ hcT, const float4* __restrict__ rwT,
        const float4* __restrict__ iwT, float* __restrict__ z) {
    int o = threadIdx.x & 63;
    int nl = threadIdx.x >> 6;
    int n = blockIdx.x * 16 + nl;
    __shared__ float saux[16][CIN];
    saux[nl][o] = y[n * CIN + o];
    __syncthreads();
    float wn = diag[n];
    const float C2 = -0.41614683654714241f;   // cos(2.0)
    const float S2 = 0.90929742682568170f;    // sin(2.0)
    float acc = 0.0f;
    for (int i = 0; i < CIN; ++i) {
        float2 hc = hcT[i * 64 + o];
        float hw = hc.x * wn;
        float t2v = hw * hw;
        float inv = 1.0f / (t2v + 1.0f);
        float c1 = (t2v - 1.0f) * inv;
        float s1 = (2.0f * hw) * inv;
        if (!(hw > 1e-5f)) { c1 = C2; s1 = S2; }
        float4 rwv = rwT[i * 64 + o];
        float4 iwv = iwT[i * 64 + o];
        float g = hc.y;
        float cj = c1, sj = s1;
        g += rwv.x * cj - iwv.x * sj;
        float cn = cj * c1 - sj * s1; float sn = sj * c1 + cj * s1; cj = cn; sj = sn;
        g += rwv.y * cj - iwv.y * sj;
        cn = cj * c1 - sj * s1; sn = sj * c1 + cj * s1; cj = cn; sj = sn;
        g += rwv.z * cj - iwv.z * sj;
        cn = cj * c1 - sj * s1; sn = sj * c1 + cj * s1; cj = cn; sj = sn;
        g += rwv.w * cj - iwv.w * sj;
        acc += g * saux[nl][i];
    }
    z[(size_t)n * COUT + o] = acc;
}

// Fused finalrot + bias + store. Blocks 0..1023: non-pivot rows. Block 1024:
// sequential rotation chain on the <=20 pivot rows (disjoint), then store them.
__global__ void store_fused_k(
        float* __restrict__ z, const float* __restrict__ bias,
        const int* __restrict__ dslot, const int* __restrict__ slistG,
        const int* __restrict__ nslotsG,
        const int* __restrict__ rotk, const int* __restrict__ rotl,
        const float* __restrict__ rotc, const float* __restrict__ rotsv,
        float* __restrict__ out) {
    int t = threadIdx.x;
    if (blockIdx.x < 1024) {
        int idx = blockIdx.x * 256 + t;
        int row = idx >> 6;
        if (dslot[row] < 0) out[idx] = z[idx] + bias[idx & 63];
    } else if (t < 64) {
        for (int i = ITERS - 1; i >= 0; --i) {
            int k = rotk[i], l = rotl[i];
            float c = rotc[i], s = rotsv[i];
            float zk = z[k * COUT + t];
            float zl = z[l * COUT + t];
            z[k * COUT + t] = c * zk + s * zl;
            z[l * COUT + t] = -s * zk + c * zl;
        }
        int ns = *nslotsG;
        for (int d = 0; d < ns; ++d) {
            int r = slistG[d];
            out[r * COUT + t] = z[r * COUT + t] + bias[t];
        }
    }
}

extern "C" void kernel_launch(void* const* d_in, const int* in_sizes, int n_in,
                              void* d_out, int out_size, void* d_ws, size_t ws_size,
                              hipStream_t stream) {
    const float* x   = (const float*)d_in[0];
    const int*   ei  = (const int*)d_in[1];
    const float* rw  = (const float*)d_in[2];
    const float* iw  = (const float*)d_in[3];
    const float* hh  = (const float*)d_in[4];
    const float* cw  = (const float*)d_in[5];
    const float* bias= (const float*)d_in[6];
    float* out = (float*)d_out;

    // Workspace carve (~7.5 MB)
    float* rowS = (float*)d_ws;                 // MAXS*N
    float* colS = rowS + (size_t)MAXS * N;      // MAXS*N
    float* y    = colS + (size_t)MAXS * N;      // N*CIN
    float* z    = y + N * CIN;                  // N*COUT
    float2* hcT = (float2*)(z + N * COUT);      // 4096 float2
    float4* rwT = (float4*)(hcT + 4096);        // 4096 float4
    float4* iwT = rwT + 4096;                   // 4096 float4
    float* dinv = (float*)(iwT + 4096);         // 4096
    float* diag = dinv + N;                     // 4096
    float* rowval = diag + N;                   // 4096
    u64* rowmax = (u64*)(rowval + N);           // 4096 u64
    int* rowptr = (int*)(rowmax + N);           // 4100
    int* fill   = rowptr + 4100;                // 4096
    int* deg    = fill + N;                     // 4096
    int* slist  = deg + N;                      // 64
    int* nslots = slist + 64;                   // 4
    int* dslot  = nslots + 4;                   // 4096
    int* rotk   = dslot + N;                    // 16
    int* rotl   = rotk + 16;                    // 16
    float* rotc = (float*)(rotl + 16);          // 16
    float* rotsv= rotc + 16;                    // 16
    int* colidx = (int*)(rotsv + 16);           // 400000

    int E = in_sizes[1] / 2;                    // 200000 (row half of edge_index)
    int eb = (E + 255) / 256;

    init_k<<<16, 256, 0, stream>>>(deg, fill, dslot);
    edges1_k<<<eb, 256, 0, stream>>>(ei, deg, E);
    scan_k<<<1, 1024, 0, stream>>>(deg, rowptr, dinv);
    edges2_k<<<eb, 256, 0, stream>>>(ei, rowptr, fill, colidx, E);
    prepw_k<<<16, 256, 0, stream>>>(hh, cw, rw, iw, hcT, rwT, iwT);
    rowmax0_k<<<N, 256, 0, stream>>>(rowptr, colidx, dinv, x, y, diag, rowmax, rowval);

    jacobi_k<<<1, 1024, 0, stream>>>(rowptr, colidx, dinv, diag, rowmax, rowval,
                                     y, rowS, colS, dslot, slist, nslots,
                                     rotk, rotl, rotc, rotsv);

    spectral_k<<<N / 16, 1024, 0, stream>>>(diag, y, hcT, rwT, iwT, z);
    store_fused_k<<<1025, 256, 0, stream>>>(z, bias, dslot, slist, nslots,
                                            rotk, rotl, rotc, rotsv, out);
}

// Round 8
// 351.984 us; speedup vs baseline: 1.0908x; 1.0908x over previous
//
#include <hip/hip_runtime.h>
#include <hip/hip_bf16.h>

// Match numpy: no FMA contraction anywhere that feeds the Jacobi pivots.
#pragma clang fp contract(off)

#define N 4096
#define CIN 64
#define COUT 64
#define ITERS 10
#define MAXS 40

typedef unsigned long long u64;

// pack (|value|, col j): bigger value wins; tie -> smaller j
__device__ __forceinline__ u64 packkey(float v, unsigned j) {
    return ((u64)__float_as_uint(v) << 32) | (u64)(~j);
}

// ---------- setup ----------
__global__ void init_k(int* __restrict__ deg, int* __restrict__ fill) {
    int i = blockIdx.x * 256 + threadIdx.x;
    if (i < N) { deg[i] = 0; fill[i] = 0; }
}

__global__ void edges1_k(const int* __restrict__ ei, int* __restrict__ deg, int E) {
    int e = blockIdx.x * 256 + threadIdx.x;
    if (e < E) atomicAdd(&deg[ei[e]], 1);
}

__global__ void __launch_bounds__(1024) scan_k(const int* __restrict__ deg,
                                               int* __restrict__ rowptr,
                                               float* __restrict__ dinv) {
    __shared__ int ps[1024];
    int t = threadIdx.x, b = t * 4;
    int d0 = deg[b], d1 = deg[b + 1], d2 = deg[b + 2], d3 = deg[b + 3];
    int local = d0 + d1 + d2 + d3;
    ps[t] = local;
    __syncthreads();
    for (int off = 1; off < 1024; off <<= 1) {
        int v = (t >= off) ? ps[t - off] : 0;
        __syncthreads();
        ps[t] += v;
        __syncthreads();
    }
    int excl = ps[t] - local;
    rowptr[b] = excl; rowptr[b + 1] = excl + d0;
    rowptr[b + 2] = excl + d0 + d1; rowptr[b + 3] = excl + d0 + d1 + d2;
    if (t == 1023) rowptr[4096] = ps[1023];
    dinv[b]     = d0 > 0 ? 1.0f / sqrtf((float)d0) : 0.0f;
    dinv[b + 1] = d1 > 0 ? 1.0f / sqrtf((float)d1) : 0.0f;
    dinv[b + 2] = d2 > 0 ? 1.0f / sqrtf((float)d2) : 0.0f;
    dinv[b + 3] = d3 > 0 ? 1.0f / sqrtf((float)d3) : 0.0f;
}

__global__ void edges2_k(const int* __restrict__ ei, const int* __restrict__ rowptr,
                         int* __restrict__ fill, int* __restrict__ colidx, int E) {
    int e = blockIdx.x * 256 + threadIdx.x;
    if (e < E) {
        int r = ei[e], c = ei[E + e];
        int pos = rowptr[r] + atomicAdd(&fill[r], 1);
        colidx[pos] = c;
    }
}

__global__ void prepw_k(const float* __restrict__ hh, const float* __restrict__ cw,
                        const float* __restrict__ rw, const float* __restrict__ iw,
                        float2* __restrict__ hcT, float4* __restrict__ rwT,
                        float4* __restrict__ iwT) {
    int idx = blockIdx.x * 256 + threadIdx.x;
    int i = idx >> 6, o = idx & 63;
    int src = o * 64 + i;
    hcT[idx] = make_float2(hh[src], cw[src]);
    rwT[idx] = make_float4(rw[src * 4 + 0], rw[src * 4 + 1], rw[src * 4 + 2], rw[src * 4 + 3]);
    iwT[idx] = make_float4(iw[src * 4 + 0], iw[src * 4 + 1], iw[src * 4 + 2], iw[src * 4 + 3]);
}

// per-row max of |L_ij| (j>i), diag, and y=x copy. One block per row.
__global__ void __launch_bounds__(256) rowmax0_k(
        const int* __restrict__ rowptr, const int* __restrict__ colidx,
        const float* __restrict__ dinv, const float* __restrict__ x,
        float* __restrict__ y, float* __restrict__ diag,
        u64* __restrict__ rowmax, float* __restrict__ rowval) {
    const int i = blockIdx.x, t = threadIdx.x;
    __shared__ float row[N];
    __shared__ u64 w4[4];
    for (int j = t; j < N; j += 256) row[j] = 0.0f;
    __syncthreads();
    for (int e = rowptr[i] + t; e < rowptr[i + 1]; e += 256)
        atomicAdd(&row[colidx[e]], 1.0f);
    __syncthreads();
    float di = dinv[i];
    u64 best = packkey(0.0f, 4095u);
    for (int j = t; j < N; j += 256) {
        if (j > i) {
            float v = -((di * row[j]) * dinv[j]);
            u64 kk = packkey(fabsf(v), (unsigned)j);
            if (kk > best) best = kk;
        }
    }
    for (int off = 32; off; off >>= 1) { u64 o = __shfl_down(best, off, 64); if (o > best) best = o; }
    if ((t & 63) == 0) w4[t >> 6] = best;
    __syncthreads();
    if (t == 0) {
        u64 b = w4[0];
        for (int w = 1; w < 4; ++w) if (w4[w] > b) b = w4[w];
        unsigned js = (~(unsigned)b) & 4095u;
        rowmax[i] = b;
        rowval[i] = -((di * row[js]) * dinv[js]);
        diag[i] = 1.0f - ((di * row[i]) * di);
    }
    if (t < CIN) y[i * CIN + t] = x[i * CIN + t];
}

// ---------- persistent single-block Jacobi: all ITERS iterations ----------
// All hot state in LDS; row+col orientations built/rotated in fused passes.
__global__ void __launch_bounds__(1024) jacobi_k(
        const int* __restrict__ rowptr, const int* __restrict__ colidx,
        const float* __restrict__ dinv,
        float* __restrict__ diag, const u64* __restrict__ rowmaxG,
        const float* __restrict__ rowvalG, float* __restrict__ y,
        float* __restrict__ rowS, float* __restrict__ colS,
        int* __restrict__ dslotG, int* __restrict__ slistG, int* __restrict__ nslotsG,
        int* __restrict__ rotk, int* __restrict__ rotl,
        float* __restrict__ rotc, float* __restrict__ rotsv) {
    __shared__ float rowK[N], rowL[N];     // row-orientation a_{k,j}, a_{l,j}  (32 KB)
    __shared__ float colK[N], colL[N];     // col-orientation a_{j,k}, a_{j,l}  (32 KB)
    __shared__ u64 rmaxL[N];               // 32 KB
    __shared__ float rvalL[N];             // 16 KB
    __shared__ float diagL[N];             // 16 KB
    __shared__ short dslotL[N];            // 8 KB
    __shared__ unsigned short sdirty[N];   // 8 KB
    __shared__ u64 w16[16], w16b[16];
    __shared__ int slistL[MAXS];
    __shared__ int S_k, S_l, S_slotk, S_slotl, S_oldk, S_oldl, S_nold, S_ns, S_snd;
    __shared__ float S_c, S_s, S_a2kk, S_a2ll;
    const int t = threadIdx.x;

    for (int i = t; i < N; i += 1024) {
        rmaxL[i] = rowmaxG[i];
        rvalL[i] = rowvalG[i];
        diagL[i] = diag[i];
        dslotL[i] = -1;
    }
    if (t == 0) S_ns = 0;
    __syncthreads();

    for (int it = 0; it < ITERS; ++it) {
        // ---- P0: pivot select (all LDS; val desc, flat idx asc = np.argmax) ----
        u64 best = 0ull;
        for (int r = t; r < N; r += 1024) {
            u64 p = rmaxL[r];
            unsigned vb = (unsigned)(p >> 32);
            unsigned j = (~(unsigned)p) & 4095u;
            unsigned flat = ((unsigned)r << 12) | j;
            u64 key = ((u64)vb << 24) | (u64)((~flat) & 0xFFFFFFu);
            if (key > best) best = key;
        }
        for (int off = 32; off; off >>= 1) { u64 o = __shfl_down(best, off, 64); if (o > best) best = o; }
        if ((t & 63) == 0) w16[t >> 6] = best;
        __syncthreads();
        if (t == 0) {
            u64 b = w16[0];
            for (int w = 1; w < 16; ++w) if (w16[w] > b) b = w16[w];
            unsigned flat = (~(unsigned)b) & 0xFFFFFFu;
            int k = (int)(flat >> 12), l = (int)(flat & 4095u);
            float akl = rvalL[k];
            float akk = diagL[k], all_ = diagL[l];
            float aDiff = all_ - akk;
            float akl_safe = (akl == 0.0f) ? 1.0f : akl;
            float aDiff_safe = (aDiff == 0.0f) ? 1.0f : aDiff;
            float phi = aDiff / (2.0f * akl_safe);
            float t2 = 1.0f / (fabsf(phi) + sqrtf(phi * phi + 1.0f));
            t2 = (phi < 0.0f) ? -t2 : t2;
            float t1 = akl / aDiff_safe;
            float tt = (fabsf(akl) < fabsf(aDiff) * 1e-36f) ? t1 : t2;
            float cv = 1.0f / sqrtf(tt * tt + 1.0f);
            float sv = tt * cv;
            rotk[it] = k; rotl[it] = l; rotc[it] = cv; rotsv[it] = sv;
            int ns = S_ns;
            S_nold = ns;
            int ok = dslotL[k]; S_oldk = ok;
            int sk = ok; if (ok < 0) { sk = ns; slistL[ns] = k; dslotL[k] = (short)ns; ns++; }
            int ol = dslotL[l]; S_oldl = ol;
            int sl = ol; if (ol < 0) { sl = ns; slistL[ns] = l; dslotL[l] = (short)ns; ns++; }
            S_ns = ns;
            S_k = k; S_l = l; S_slotk = sk; S_slotl = sl; S_c = cv; S_s = sv;
        }
        __syncthreads();
        const int k = S_k, l = S_l, slotk = S_slotk, slotl = S_slotl;
        const int oldk = S_oldk, oldl = S_oldl, nold = S_nold;
        const float c = S_c, s = S_s;
        const bool freshK = (oldk < 0), freshL = (oldl < 0);
        // ---- P1: incremental U^T x (global; no intra-kernel reader) ----
        if (t < CIN) {
            float yk = y[k * CIN + t], yl = y[l * CIN + t];
            y[k * CIN + t] = c * yk - s * yl;
            y[l * CIN + t] = s * yk + c * yl;
        }
        const float dk = dinv[k], dl = dinv[l];

        // ---- P2: counts for fresh pivots (block-uniform branch) ----
        if (freshK || freshL) {
            for (int j = t; j < N; j += 1024) {
                if (freshK) rowK[j] = 0.0f;
                if (freshL) rowL[j] = 0.0f;
            }
            __syncthreads();
            if (freshK) for (int e = rowptr[k] + t; e < rowptr[k + 1]; e += 1024) atomicAdd(&rowK[colidx[e]], 1.0f);
            if (freshL) for (int e = rowptr[l] + t; e < rowptr[l + 1]; e += 1024) atomicAdd(&rowL[colidx[e]], 1.0f);
            __syncthreads();
        }
        // ---- P3: build both orientations in one pass ----
        for (int j = t; j < N; j += 1024) {
            float dj = dinv[j];
            if (freshK) {
                float cnt = rowK[j];
                rowK[j] = -((dk * cnt) * dj);    // a_{k,j} reference orientation
                colK[j] = -((dj * cnt) * dk);    // a_{j,k} reference orientation
            } else {
                rowK[j] = rowS[(size_t)oldk * N + j];
                colK[j] = colS[(size_t)oldk * N + j];
            }
            if (freshL) {
                float cnt = rowL[j];
                rowL[j] = -((dl * cnt) * dj);
                colL[j] = -((dj * cnt) * dl);
            } else {
                rowL[j] = rowS[(size_t)oldl * N + j];
                colL[j] = colS[(size_t)oldl * N + j];
            }
        }
        __syncthreads();
        // ---- P4: overlays at old-pivot positions (exact stored values) ----
        if (t < nold) {
            int js = slistL[t];
            if (freshK) rowK[js] = colS[(size_t)t * N + k];      // a_{k,js}
            if (freshL) rowL[js] = colS[(size_t)t * N + l];      // a_{l,js}
            if (js != k && js != l) {
                if (freshK) colK[js] = rowS[(size_t)t * N + k];  // a_{js,k}
                if (freshL) colL[js] = rowS[(size_t)t * N + l];  // a_{js,l}
            }
        }
        if (t == 1) S_snd = 0;
        __syncthreads();
        // ---- P5: 2x2 block, exact reference op order (all LDS) ----
        if (t == 0) {
            rowK[k] = diagL[k]; rowL[l] = diagL[l];
            float akk = rowK[k], all_ = rowL[l], akl = rowK[l], alk = rowL[k];
            float a1kk = c * akk - s * akl;
            float a1kl = s * akk + c * akl;
            float a1lk = c * alk - s * all_;
            float a1ll = s * alk + c * all_;
            S_a2kk = c * a1kk - s * a1lk;
            S_a2ll = s * a1kl + c * a1ll;
            diagL[k] = S_a2kk; diagL[l] = S_a2ll;
        }
        __syncthreads();
        const float a2kk = S_a2kk, a2ll = S_a2ll;
        // ---- P6: rotate all four arrays in ONE pass; write rowS/colS; k/l rowmax ----
        u64 bk = packkey(0.0f, 4095u), bl = packkey(0.0f, 4095u);
        for (int j = t; j < N; j += 1024) {
            float rk_ = rowK[j], rl_ = rowL[j];
            float ck_ = colK[j], cl_ = colL[j];
            float nrk, nrl, nck, ncl;
            if (j == k)      { nrk = a2kk; nrl = 0.0f; nck = a2kk; ncl = 0.0f; }
            else if (j == l) { nrk = 0.0f; nrl = a2ll; nck = 0.0f; ncl = a2ll; }
            else {
                nrk = c * rk_ - s * rl_; nrl = s * rk_ + c * rl_;
                nck = c * ck_ - s * cl_; ncl = s * ck_ + c * cl_;
            }
            rowK[j] = nrk; rowL[j] = nrl; colK[j] = nck; colL[j] = ncl;
            rowS[(size_t)slotk * N + j] = nrk;
            rowS[(size_t)slotl * N + j] = nrl;
            colS[(size_t)slotk * N + j] = nck;
            colS[(size_t)slotl * N + j] = ncl;
            if (j > k) { u64 kk = packkey(fabsf(nrk), (unsigned)j); if (kk > bk) bk = kk; }
            if (j > l) { u64 kk = packkey(fabsf(nrl), (unsigned)j); if (kk > bl) bl = kk; }
        }
        for (int off = 32; off; off >>= 1) {
            u64 o = __shfl_down(bk, off, 64); if (o > bk) bk = o;
            u64 o2 = __shfl_down(bl, off, 64); if (o2 > bl) bl = o2;
        }
        if ((t & 63) == 0) { w16[t >> 6] = bk; w16b[t >> 6] = bl; }
        __syncthreads();
        if (t == 0) {
            u64 b1 = w16[0], b2 = w16b[0];
            for (int w = 1; w < 16; ++w) { if (w16[w] > b1) b1 = w16[w]; if (w16b[w] > b2) b2 = w16b[w]; }
            unsigned j1 = (~(unsigned)b1) & 4095u, j2 = (~(unsigned)b2) & 4095u;
            rmaxL[k] = b1; rvalL[k] = rowK[j1];
            rmaxL[l] = b2; rvalL[l] = rowL[j2];
        }
        // ---- P7 (same phase): patch old slots + merge rowmax for other rows ----
        if (t < nold) {
            int js = slistL[t];
            if (js != k && js != l) {
                colS[(size_t)t * N + k] = rowK[js];   // new a_{k,js}
                colS[(size_t)t * N + l] = rowL[js];   // new a_{l,js}
                rowS[(size_t)t * N + k] = colK[js];   // new a_{js,k}
                rowS[(size_t)t * N + l] = colL[js];   // new a_{js,l}
            }
        }
        for (int i = t; i < N; i += 1024) {
            if (i == k || i == l) continue;
            float nik = colK[i];          // new a_{i,k}
            float nil = colL[i];          // new a_{i,l}
            u64 cached = rmaxL[i];
            unsigned cj = (~(unsigned)cached) & 4095u;
            bool kc = (k > i), lc = (l > i);
            u64 ck_ = kc ? packkey(fabsf(nik), (unsigned)k) : 0ull;
            u64 cl_ = lc ? packkey(fabsf(nil), (unsigned)l) : 0ull;
            bool stale = false; u64 base = cached; bool useOld = true;
            if (kc && cj == (unsigned)k)      { if (ck_ < cached) stale = true; else { base = 0ull; useOld = false; } }
            else if (lc && cj == (unsigned)l) { if (cl_ < cached) stale = true; else { base = 0ull; useOld = false; } }
            if (!stale) {
                if (kc || lc) {
                    u64 m = base; float mv = useOld ? rvalL[i] : 0.0f;
                    if (ck_ > m) { m = ck_; mv = nik; }
                    if (cl_ > m) { m = cl_; mv = nil; }
                    rmaxL[i] = m; rvalL[i] = mv;
                }
            } else {
                int d = atomicAdd(&S_snd, 1);
                sdirty[d] = (unsigned short)i;
            }
        }
        __syncthreads();
        // ---- P8: dirty rescans (rare) ----
        const int nd = S_snd;
        const int ns2 = S_ns;
        for (int d = 0; d < nd; ++d) {
            int ir = sdirty[d];
            int slot = dslotL[ir];
            u64 bb = packkey(0.0f, 4095u);
            if (slot >= 0) {   // former pivot: stored dense row (substitute k,l from LDS)
                for (int j = t; j < N; j += 1024) {
                    if (j > ir) {
                        float v = (j == k) ? colK[ir] : (j == l) ? colL[ir]
                                  : rowS[(size_t)slot * N + j];
                        u64 kk = packkey(fabsf(v), (unsigned)j);
                        if (kk > bb) bb = kk;
                    }
                }
                for (int off = 32; off; off >>= 1) { u64 o = __shfl_down(bb, off, 64); if (o > bb) bb = o; }
                if ((t & 63) == 0) w16[t >> 6] = bb;
                __syncthreads();
                if (t == 0) {
                    u64 b = w16[0];
                    for (int w = 1; w < 16; ++w) if (w16[w] > b) b = w16[w];
                    unsigned js = (~(unsigned)b) & 4095u;
                    rmaxL[ir] = b;
                    rvalL[ir] = (js == (unsigned)k) ? colK[ir] : (js == (unsigned)l) ? colL[ir]
                                : rowS[(size_t)slot * N + js];
                }
                __syncthreads();
            } else {           // rebuild row ir from CSR + slot overlays (scratch = rowK)
                for (int j = t; j < N; j += 1024) rowK[j] = 0.0f;
                __syncthreads();
                for (int e = rowptr[ir] + t; e < rowptr[ir + 1]; e += 1024)
                    atomicAdd(&rowK[colidx[e]], 1.0f);
                __syncthreads();
                float di = dinv[ir];
                for (int j = t; j < N; j += 1024) rowK[j] = -((di * rowK[j]) * dinv[j]);
                __syncthreads();
                if (t < ns2) {
                    int js = slistL[t];
                    if (js != ir) {
                        float v = (t == slotk) ? colK[ir] : (t == slotl) ? colL[ir]
                                  : colS[(size_t)t * N + ir];
                        rowK[js] = v;
                    }
                }
                __syncthreads();
                for (int j = t; j < N; j += 1024) {
                    if (j > ir) { u64 kk = packkey(fabsf(rowK[j]), (unsigned)j); if (kk > bb) bb = kk; }
                }
                for (int off = 32; off; off >>= 1) { u64 o = __shfl_down(bb, off, 64); if (o > bb) bb = o; }
                if ((t & 63) == 0) w16[t >> 6] = bb;
                __syncthreads();
                if (t == 0) {
                    u64 b = w16[0];
                    for (int w = 1; w < 16; ++w) if (w16[w] > b) b = w16[w];
                    unsigned js = (~(unsigned)b) & 4095u;
                    rmaxL[ir] = b; rvalL[ir] = rowK[js];
                }
                __syncthreads();
            }
        }
    }
    // epilogue: mirror state for tail kernels
    for (int i = t; i < N; i += 1024) {
        diag[i] = diagL[i];
        dslotG[i] = (int)dslotL[i];
    }
    if (t < S_ns) slistG[t] = slistL[t];
    if (t == 0) *nslotsG = S_ns;
}

// ---------- tail ----------
__global__ void __launch_bounds__(1024) spectral_k(
        const float* __restrict__ diag, const float* __restrict__ y,
        const float2* __restrict__ hcT, const float4* __restrict__ rwT,
        const float4* __restrict__ iwT, float* __restrict__ z) {
    int o = threadIdx.x & 63;
    int nl = threadIdx.x >> 6;
    int n = blockIdx.x * 16 + nl;
    __shared__ float saux[16][CIN];
    saux[nl][o] = y[n * CIN + o];
    __syncthreads();
    float wn = diag[n];
    const float C2 = -0.41614683654714241f;   // cos(2.0)
    const float S2 = 0.90929742682568170f;    // sin(2.0)
    float acc = 0.0f;
    for (int i = 0; i < CIN; ++i) {
        float2 hc = hcT[i * 64 + o];
        float hw = hc.x * wn;
        float t2v = hw * hw;
        float inv = 1.0f / (t2v + 1.0f);
        float c1 = (t2v - 1.0f) * inv;
        float s1 = (2.0f * hw) * inv;
        if (!(hw > 1e-5f)) { c1 = C2; s1 = S2; }
        float4 rwv = rwT[i * 64 + o];
        float4 iwv = iwT[i * 64 + o];
        float g = hc.y;
        float cj = c1, sj = s1;
        g += rwv.x * cj - iwv.x * sj;
        float cn = cj * c1 - sj * s1; float sn = sj * c1 + cj * s1; cj = cn; sj = sn;
        g += rwv.y * cj - iwv.y * sj;
        cn = cj * c1 - sj * s1; sn = sj * c1 + cj * s1; cj = cn; sj = sn;
        g += rwv.z * cj - iwv.z * sj;
        cn = cj * c1 - sj * s1; sn = sj * c1 + cj * s1; cj = cn; sj = sn;
        g += rwv.w * cj - iwv.w * sj;
        acc += g * saux[nl][i];
    }
    z[(size_t)n * COUT + o] = acc;
}

// Fused finalrot + bias + store. Blocks 0..1023: non-pivot rows. Block 1024:
// sequential rotation chain on the <=20 pivot rows (disjoint), then store them.
__global__ void store_fused_k(
        float* __restrict__ z, const float* __restrict__ bias,
        const int* __restrict__ dslot, const int* __restrict__ slistG,
        const int* __restrict__ nslotsG,
        const int* __restrict__ rotk, const int* __restrict__ rotl,
        const float* __restrict__ rotc, const float* __restrict__ rotsv,
        float* __restrict__ out) {
    int t = threadIdx.x;
    if (blockIdx.x < 1024) {
        int idx = blockIdx.x * 256 + t;
        int row = idx >> 6;
        if (dslot[row] < 0) out[idx] = z[idx] + bias[idx & 63];
    } else if (t < 64) {
        for (int i = ITERS - 1; i >= 0; --i) {
            int k = rotk[i], l = rotl[i];
            float c = rotc[i], s = rotsv[i];
            float zk = z[k * COUT + t];
            float zl = z[l * COUT + t];
            z[k * COUT + t] = c * zk + s * zl;
            z[l * COUT + t] = -s * zk + c * zl;
        }
        int ns = *nslotsG;
        for (int d = 0; d < ns; ++d) {
            int r = slistG[d];
            out[r * COUT + t] = z[r * COUT + t] + bias[t];
        }
    }
}

extern "C" void kernel_launch(void* const* d_in, const int* in_sizes, int n_in,
                              void* d_out, int out_size, void* d_ws, size_t ws_size,
                              hipStream_t stream) {
    const float* x   = (const float*)d_in[0];
    const int*   ei  = (const int*)d_in[1];
    const float* rw  = (const float*)d_in[2];
    const float* iw  = (const float*)d_in[3];
    const float* hh  = (const float*)d_in[4];
    const float* cw  = (const float*)d_in[5];
    const float* bias= (const float*)d_in[6];
    float* out = (float*)d_out;

    // Workspace carve (~7.5 MB)
    float* rowS = (float*)d_ws;                 // MAXS*N
    float* colS = rowS + (size_t)MAXS * N;      // MAXS*N
    float* y    = colS + (size_t)MAXS * N;      // N*CIN
    float* z    = y + N * CIN;                  // N*COUT
    float2* hcT = (float2*)(z + N * COUT);      // 4096 float2
    float4* rwT = (float4*)(hcT + 4096);        // 4096 float4
    float4* iwT = rwT + 4096;                   // 4096 float4
    float* dinv = (float*)(iwT + 4096);         // 4096
    float* diag = dinv + N;                     // 4096
    float* rowval = diag + N;                   // 4096
    u64* rowmax = (u64*)(rowval + N);           // 4096 u64
    int* rowptr = (int*)(rowmax + N);           // 4100
    int* fill   = rowptr + 4100;                // 4096
    int* deg    = fill + N;                     // 4096
    int* slist  = deg + N;                      // 64
    int* nslots = slist + 64;                   // 4
    int* dslot  = nslots + 4;                   // 4096
    int* rotk   = dslot + N;                    // 16
    int* rotl   = rotk + 16;                    // 16
    float* rotc = (float*)(rotl + 16);          // 16
    float* rotsv= rotc + 16;                    // 16
    int* colidx = (int*)(rotsv + 16);           // 400000

    int E = in_sizes[1] / 2;                    // row half of edge_index
    int eb = (E + 255) / 256;

    init_k<<<16, 256, 0, stream>>>(deg, fill);
    edges1_k<<<eb, 256, 0, stream>>>(ei, deg, E);
    scan_k<<<1, 1024, 0, stream>>>(deg, rowptr, dinv);
    edges2_k<<<eb, 256, 0, stream>>>(ei, rowptr, fill, colidx, E);
    prepw_k<<<16, 256, 0, stream>>>(hh, cw, rw, iw, hcT, rwT, iwT);
    rowmax0_k<<<N, 256, 0, stream>>>(rowptr, colidx, dinv, x, y, diag, rowmax, rowval);

    jacobi_k<<<1, 1024, 0, stream>>>(rowptr, colidx, dinv, diag, rowmax, rowval,
                                     y, rowS, colS, dslot, slist, nslots,
                                     rotk, rotl, rotc, rotsv);

    spectral_k<<<N / 16, 1024, 0, stream>>>(diag, y, hcT, rwT, iwT, z);
    store_fused_k<<<1025, 256, 0, stream>>>(z, bias, dslot, slist, nslots,
                                            rotk, rotl, rotc, rotsv, out);
}

// Round 9
// 284.607 us; speedup vs baseline: 1.3490x; 1.2367x over previous
//
#include <hip/hip_runtime.h>
#include <hip/hip_bf16.h>

// Match numpy: no FMA contraction anywhere that feeds the Jacobi pivots.
#pragma clang fp contract(off)

#define N 4096
#define CIN 64
#define COUT 64
#define ITERS 10
#define MAXS 40

typedef unsigned long long u64;

// pack (|value|, col j): bigger value wins; tie -> smaller j
__device__ __forceinline__ u64 packkey(float v, unsigned j) {
    return ((u64)__float_as_uint(v) << 32) | (u64)(~j);
}

// ---------- setup ----------
__global__ void init_k(int* __restrict__ deg, int* __restrict__ fill) {
    int i = blockIdx.x * 256 + threadIdx.x;
    if (i < N) { deg[i] = 0; fill[i] = 0; }
}

__global__ void edges1_k(const int* __restrict__ ei, int* __restrict__ deg, int E) {
    int e = blockIdx.x * 256 + threadIdx.x;
    if (e < E) atomicAdd(&deg[ei[e]], 1);
}

__global__ void __launch_bounds__(1024) scan_k(const int* __restrict__ deg,
                                               int* __restrict__ rowptr,
                                               float* __restrict__ dinv) {
    __shared__ int ps[1024];
    int t = threadIdx.x, b = t * 4;
    int d0 = deg[b], d1 = deg[b + 1], d2 = deg[b + 2], d3 = deg[b + 3];
    int local = d0 + d1 + d2 + d3;
    ps[t] = local;
    __syncthreads();
    for (int off = 1; off < 1024; off <<= 1) {
        int v = (t >= off) ? ps[t - off] : 0;
        __syncthreads();
        ps[t] += v;
        __syncthreads();
    }
    int excl = ps[t] - local;
    rowptr[b] = excl; rowptr[b + 1] = excl + d0;
    rowptr[b + 2] = excl + d0 + d1; rowptr[b + 3] = excl + d0 + d1 + d2;
    if (t == 1023) rowptr[4096] = ps[1023];
    dinv[b]     = d0 > 0 ? 1.0f / sqrtf((float)d0) : 0.0f;
    dinv[b + 1] = d1 > 0 ? 1.0f / sqrtf((float)d1) : 0.0f;
    dinv[b + 2] = d2 > 0 ? 1.0f / sqrtf((float)d2) : 0.0f;
    dinv[b + 3] = d3 > 0 ? 1.0f / sqrtf((float)d3) : 0.0f;
}

__global__ void edges2_k(const int* __restrict__ ei, const int* __restrict__ rowptr,
                         int* __restrict__ fill, int* __restrict__ colidx, int E) {
    int e = blockIdx.x * 256 + threadIdx.x;
    if (e < E) {
        int r = ei[e], c = ei[E + e];
        int pos = rowptr[r] + atomicAdd(&fill[r], 1);
        colidx[pos] = c;
    }
}

__global__ void prepw_k(const float* __restrict__ hh, const float* __restrict__ cw,
                        const float* __restrict__ rw, const float* __restrict__ iw,
                        float2* __restrict__ hcT, float4* __restrict__ rwT,
                        float4* __restrict__ iwT) {
    int idx = blockIdx.x * 256 + threadIdx.x;
    int i = idx >> 6, o = idx & 63;
    int src = o * 64 + i;
    hcT[idx] = make_float2(hh[src], cw[src]);
    rwT[idx] = make_float4(rw[src * 4 + 0], rw[src * 4 + 1], rw[src * 4 + 2], rw[src * 4 + 3]);
    iwT[idx] = make_float4(iw[src * 4 + 0], iw[src * 4 + 1], iw[src * 4 + 2], iw[src * 4 + 3]);
}

// per-row max of |L_ij| (j>i), diag, and y=x copy. One block per row.
// Only the upper triangle (j>=i) is materialized.
__global__ void __launch_bounds__(256) rowmax0_k(
        const int* __restrict__ rowptr, const int* __restrict__ colidx,
        const float* __restrict__ dinv, const float* __restrict__ x,
        float* __restrict__ y, float* __restrict__ diag,
        u64* __restrict__ rowmax, float* __restrict__ rowval) {
    const int i = blockIdx.x, t = threadIdx.x;
    __shared__ float row[N];
    __shared__ u64 w4[4];
    for (int j = i + t; j < N; j += 256) row[j] = 0.0f;
    __syncthreads();
    for (int e = rowptr[i] + t; e < rowptr[i + 1]; e += 256) {
        int c = colidx[e];
        if (c >= i) atomicAdd(&row[c], 1.0f);
    }
    __syncthreads();
    float di = dinv[i];
    u64 best = packkey(0.0f, 4095u);
    for (int j = i + 1 + t; j < N; j += 256) {
        float v = -((di * row[j]) * dinv[j]);
        u64 kk = packkey(fabsf(v), (unsigned)j);
        if (kk > best) best = kk;
    }
    for (int off = 32; off; off >>= 1) { u64 o = __shfl_down(best, off, 64); if (o > best) best = o; }
    if ((t & 63) == 0) w4[t >> 6] = best;
    __syncthreads();
    if (t == 0) {
        u64 b = w4[0];
        for (int w = 1; w < 4; ++w) if (w4[w] > b) b = w4[w];
        unsigned js = (~(unsigned)b) & 4095u;
        rowmax[i] = b;
        rowval[i] = -((di * row[js]) * dinv[js]);
        diag[i] = 1.0f - ((di * row[i]) * di);
    }
    if (t < CIN) y[i * CIN + t] = x[i * CIN + t];
}

// ---------- persistent single-block Jacobi: all ITERS iterations ----------
// One fused N-pass per iteration (build+overlay+rotate+store+merge);
// dirty rescans processed 4 rows at a time by 256-thread groups.
__global__ void __launch_bounds__(1024) jacobi_k(
        const int* __restrict__ rowptr, const int* __restrict__ colidx,
        const float* __restrict__ dinv,
        float* __restrict__ diag, const u64* __restrict__ rowmaxG,
        const float* __restrict__ rowvalG, float* __restrict__ y,
        float* __restrict__ rowS, float* __restrict__ colS,
        int* __restrict__ dslotG, int* __restrict__ slistG, int* __restrict__ nslotsG,
        int* __restrict__ rotk, int* __restrict__ rotl,
        float* __restrict__ rotc, float* __restrict__ rotsv) {
    __shared__ float scratch4[4 * N];      // 64 KB: counts (cntK/cntL) + dirty scratch
    __shared__ u64 rmaxL[N];               // 32 KB
    __shared__ float rvalL[N];             // 16 KB
    __shared__ float diagL[N];             // 16 KB
    __shared__ short dslotL[N];            // 8 KB
    __shared__ unsigned short sdirty[N];   // 8 KB
    __shared__ u64 w16[16], w16b[16];
    __shared__ float ovRowK[MAXS], ovRowL[MAXS], ovColK[MAXS], ovColL[MAXS];
    __shared__ float sgSub[4][2];
    __shared__ int slistL[MAXS];
    __shared__ int S_k, S_l, S_slotk, S_slotl, S_oldk, S_oldl, S_nold, S_ns, S_snd;
    __shared__ float S_c, S_s, S_a2kk, S_a2ll;
    const int t = threadIdx.x;
    float* cntK = scratch4;
    float* cntL = scratch4 + N;

    for (int i = t; i < N; i += 1024) {
        rmaxL[i] = rowmaxG[i];
        rvalL[i] = rowvalG[i];
        diagL[i] = diag[i];
        dslotL[i] = -1;
    }
    if (t == 0) S_ns = 0;
    __syncthreads();

    for (int it = 0; it < ITERS; ++it) {
        // ---- B0: pivot select (LDS; val desc, flat idx asc = np.argmax) ----
        u64 best = 0ull;
        for (int r = t; r < N; r += 1024) {
            u64 p = rmaxL[r];
            unsigned vb = (unsigned)(p >> 32);
            unsigned j = (~(unsigned)p) & 4095u;
            unsigned flat = ((unsigned)r << 12) | j;
            u64 key = ((u64)vb << 24) | (u64)((~flat) & 0xFFFFFFu);
            if (key > best) best = key;
        }
        for (int off = 32; off; off >>= 1) { u64 o = __shfl_down(best, off, 64); if (o > best) best = o; }
        if ((t & 63) == 0) w16[t >> 6] = best;
        __syncthreads();
        // ---- B1: t==0 computes rotation + 2x2 + slot bookkeeping ----
        if (t == 0) {
            u64 b = w16[0];
            for (int w = 1; w < 16; ++w) if (w16[w] > b) b = w16[w];
            unsigned flat = (~(unsigned)b) & 0xFFFFFFu;
            int k = (int)(flat >> 12), l = (int)(flat & 4095u);
            float akl = rvalL[k];                  // pivot row k's argmax IS l
            float akk = diagL[k], all_ = diagL[l];
            float aDiff = all_ - akk;
            float akl_safe = (akl == 0.0f) ? 1.0f : akl;
            float aDiff_safe = (aDiff == 0.0f) ? 1.0f : aDiff;
            float phi = aDiff / (2.0f * akl_safe);
            float t2 = 1.0f / (fabsf(phi) + sqrtf(phi * phi + 1.0f));
            t2 = (phi < 0.0f) ? -t2 : t2;
            float t1 = akl / aDiff_safe;
            float tt = (fabsf(akl) < fabsf(aDiff) * 1e-36f) ? t1 : t2;
            float cv = 1.0f / sqrtf(tt * tt + 1.0f);
            float sv = tt * cv;
            rotk[it] = k; rotl[it] = l; rotc[it] = cv; rotsv[it] = sv;
            // 2x2 block, exact reference op order
            float a1kk = cv * akk - sv * akl;
            float a1kl = sv * akk + cv * akl;
            float a1lk = cv * akl - sv * all_;     // a_{l,k} == a_{k,l} (symmetric)
            float a1ll = sv * akl + cv * all_;
            S_a2kk = cv * a1kk - sv * a1lk;
            S_a2ll = sv * a1kl + cv * a1ll;
            diagL[k] = S_a2kk; diagL[l] = S_a2ll;
            int ns = S_ns;
            S_nold = ns;
            int ok = dslotL[k]; S_oldk = ok;
            int sk = ok; if (ok < 0) { sk = ns; slistL[ns] = k; dslotL[k] = (short)ns; ns++; }
            int ol = dslotL[l]; S_oldl = ol;
            int sl = ol; if (ol < 0) { sl = ns; slistL[ns] = l; dslotL[l] = (short)ns; ns++; }
            S_ns = ns;
            S_k = k; S_l = l; S_slotk = sk; S_slotl = sl; S_c = cv; S_s = sv;
            S_snd = 0;
        }
        __syncthreads();
        const int k = S_k, l = S_l, slotk = S_slotk, slotl = S_slotl;
        const int oldk = S_oldk, oldl = S_oldl, nold = S_nold;
        const float c = S_c, s = S_s;
        const float a2kk = S_a2kk, a2ll = S_a2ll;
        const bool freshK = (oldk < 0), freshL = (oldl < 0);
        const float dk = dinv[k], dl = dinv[l];
        // ---- B2 segment: y-rot, overlay preloads, zero counts ----
        if (t < CIN) {
            float yk = y[k * CIN + t], yl = y[l * CIN + t];
            y[k * CIN + t] = c * yk - s * yl;
            y[l * CIN + t] = s * yk + c * yl;
        }
        if (t >= 64 && t < 64 + nold) {        // overlay values for fresh rows/cols
            int sl2 = t - 64;
            if (freshK) { ovRowK[sl2] = colS[(size_t)sl2 * N + k]; ovColK[sl2] = rowS[(size_t)sl2 * N + k]; }
            if (freshL) { ovRowL[sl2] = colS[(size_t)sl2 * N + l]; ovColL[sl2] = rowS[(size_t)sl2 * N + l]; }
        }
        if (freshK) for (int j = t; j < N; j += 1024) cntK[j] = 0.0f;
        if (freshL) for (int j = t; j < N; j += 1024) cntL[j] = 0.0f;
        __syncthreads();
        // ---- B3: scatter counts for fresh pivots ----
        if (freshK || freshL) {
            if (freshK) for (int e = rowptr[k] + t; e < rowptr[k + 1]; e += 1024) atomicAdd(&cntK[colidx[e]], 1.0f);
            if (freshL) for (int e = rowptr[l] + t; e < rowptr[l + 1]; e += 1024) atomicAdd(&cntL[colidx[e]], 1.0f);
            __syncthreads();
        }
        // ---- B4: THE fused pass: build + overlay + rotate + store + merge ----
        u64 bk = packkey(0.0f, 4095u), bl = packkey(0.0f, 4095u);
        {
            const int j0 = t * 4;
            float4 dj4 = *reinterpret_cast<const float4*>(dinv + j0);
            float4 bK4, bL4, cK4, cL4;
            if (freshK) {
                float4 cnt = *reinterpret_cast<const float4*>(cntK + j0);
#pragma unroll
                for (int m = 0; m < 4; ++m) {
                    float cn = (&cnt.x)[m], dj = (&dj4.x)[m];
                    (&bK4.x)[m] = -((dk * cn) * dj);
                    (&cK4.x)[m] = -((dj * cn) * dk);
                }
            } else {
                bK4 = *reinterpret_cast<const float4*>(rowS + (size_t)oldk * N + j0);
                cK4 = *reinterpret_cast<const float4*>(colS + (size_t)oldk * N + j0);
            }
            if (freshL) {
                float4 cnt = *reinterpret_cast<const float4*>(cntL + j0);
#pragma unroll
                for (int m = 0; m < 4; ++m) {
                    float cn = (&cnt.x)[m], dj = (&dj4.x)[m];
                    (&bL4.x)[m] = -((dl * cn) * dj);
                    (&cL4.x)[m] = -((dj * cn) * dl);
                }
            } else {
                bL4 = *reinterpret_cast<const float4*>(rowS + (size_t)oldl * N + j0);
                cL4 = *reinterpret_cast<const float4*>(colS + (size_t)oldl * N + j0);
            }
            float4 nrK4, nrL4, ncK4, ncL4;
#pragma unroll
            for (int m = 0; m < 4; ++m) {
                int j = j0 + m;
                float bK = (&bK4.x)[m], bL = (&bL4.x)[m];
                float cK = (&cK4.x)[m], cL = (&cL4.x)[m];
                float nrk, nrl, nck, ncl;
                if (j == k)      { nrk = a2kk; nrl = 0.0f; nck = a2kk; ncl = 0.0f; }
                else if (j == l) { nrk = 0.0f; nrl = a2ll; nck = 0.0f; ncl = a2ll; }
                else {
                    int sl2 = dslotL[j];
                    if (sl2 >= 0 && sl2 < nold) {   // old-slot overlays (fresh only)
                        if (freshK) { bK = ovRowK[sl2]; cK = ovColK[sl2]; }
                        if (freshL) { bL = ovRowL[sl2]; cL = ovColL[sl2]; }
                    }
                    nrk = c * bK - s * bL; nrl = s * bK + c * bL;
                    nck = c * cK - s * cL; ncl = s * cK + c * cL;
                }
                (&nrK4.x)[m] = nrk; (&nrL4.x)[m] = nrl;
                (&ncK4.x)[m] = nck; (&ncL4.x)[m] = ncl;
                if (j > k) { u64 kk = packkey(fabsf(nrk), (unsigned)j); if (kk > bk) bk = kk; }
                if (j > l) { u64 kk = packkey(fabsf(nrl), (unsigned)j); if (kk > bl) bl = kk; }
                // in-pass merge for row j (skip pivot rows)
                if (j != k && j != l) {
                    u64 cached = rmaxL[j];
                    unsigned cj = (~(unsigned)cached) & 4095u;
                    bool kc = (k > j), lc = (l > j);
                    u64 ckk = kc ? packkey(fabsf(nck), (unsigned)k) : 0ull;
                    u64 cll = lc ? packkey(fabsf(ncl), (unsigned)l) : 0ull;
                    bool stale = false; u64 base = cached; bool useOld = true;
                    if (kc && cj == (unsigned)k)      { if (ckk < cached) stale = true; else { base = 0ull; useOld = false; } }
                    else if (lc && cj == (unsigned)l) { if (cll < cached) stale = true; else { base = 0ull; useOld = false; } }
                    if (!stale) {
                        if (kc || lc) {
                            u64 mm = base; float mv = useOld ? rvalL[j] : 0.0f;
                            if (ckk > mm) { mm = ckk; mv = nck; }
                            if (cll > mm) { mm = cll; mv = ncl; }
                            rmaxL[j] = mm; rvalL[j] = mv;
                        }
                    } else {
                        int d = atomicAdd(&S_snd, 1);
                        sdirty[d] = (unsigned short)j;
                    }
                }
            }
            *reinterpret_cast<float4*>(rowS + (size_t)slotk * N + j0) = nrK4;
            *reinterpret_cast<float4*>(rowS + (size_t)slotl * N + j0) = nrL4;
            *reinterpret_cast<float4*>(colS + (size_t)slotk * N + j0) = ncK4;
            *reinterpret_cast<float4*>(colS + (size_t)slotl * N + j0) = ncL4;
        }
        for (int off = 32; off; off >>= 1) {
            u64 o = __shfl_down(bk, off, 64); if (o > bk) bk = o;
            u64 o2 = __shfl_down(bl, off, 64); if (o2 > bl) bl = o2;
        }
        if ((t & 63) == 0) { w16[t >> 6] = bk; w16b[t >> 6] = bl; }
        __syncthreads();
        // ---- B5: k/l rowmax fixups + patches of old slot images ----
        if (t == 0) {
            u64 b1 = w16[0], b2 = w16b[0];
            for (int w = 1; w < 16; ++w) { if (w16[w] > b1) b1 = w16[w]; if (w16b[w] > b2) b2 = w16b[w]; }
            unsigned j1 = (~(unsigned)b1) & 4095u, j2 = (~(unsigned)b2) & 4095u;
            rmaxL[k] = b1; rvalL[k] = rowS[(size_t)slotk * N + j1];
            rmaxL[l] = b2; rvalL[l] = rowS[(size_t)slotl * N + j2];
        }
        if (t >= 64 && t < 64 + nold) {        // patch stored images of old pivots at k,l
            int sl2 = t - 64;
            int js = slistL[sl2];
            if (js != k && js != l) {
                colS[(size_t)sl2 * N + k] = rowS[(size_t)slotk * N + js];  // a_{k,js}
                colS[(size_t)sl2 * N + l] = rowS[(size_t)slotl * N + js];  // a_{l,js}
                rowS[(size_t)sl2 * N + k] = colS[(size_t)slotk * N + js];  // a_{js,k}
                rowS[(size_t)sl2 * N + l] = colS[(size_t)slotl * N + js];  // a_{js,l}
            }
        }
        __syncthreads();
        // ---- B6..: dirty rescans, 4 rows per round (256-thread groups) ----
        const int nd = S_snd;
        const int g = t >> 8, tl = t & 255;
        for (int r0 = 0; r0 < nd; r0 += 4) {
            int didx = r0 + g;
            int ir = -1, slot = -1;
            float di2 = 0.0f;
            bool active = (didx < nd);
            if (active) {
                ir = sdirty[didx];
                slot = dslotL[ir];
                di2 = dinv[ir];
            }
            float* sc = scratch4 + g * N;
            // prep: zero scratch (rebuild rows) + substitution preload
            if (active && slot < 0) {
                for (int j = tl; j < N; j += 256) sc[j] = 0.0f;
            }
            if (active && tl == 0) {
                sgSub[g][0] = colS[(size_t)slotk * N + ir];   // new a_{ir,k}
                sgSub[g][1] = colS[(size_t)slotl * N + ir];   // new a_{ir,l}
            }
            __syncthreads();
            if (active && slot < 0) {
                for (int e = rowptr[ir] + tl; e < rowptr[ir + 1]; e += 256)
                    atomicAdd(&sc[colidx[e]], 1.0f);
            }
            __syncthreads();
            u64 bb = packkey(0.0f, 4095u);
            if (active) {
                float subK = sgSub[g][0], subL = sgSub[g][1];
                if (slot >= 0) {      // former pivot: stored row with k/l substitution
                    for (int jb = tl * 4; jb < N; jb += 1024) {
                        float4 v4 = *reinterpret_cast<const float4*>(rowS + (size_t)slot * N + jb);
#pragma unroll
                        for (int m = 0; m < 4; ++m) {
                            int j = jb + m;
                            if (j <= ir) continue;
                            float v = (j == k) ? subK : (j == l) ? subL : (&v4.x)[m];
                            u64 kk = packkey(fabsf(v), (unsigned)j);
                            if (kk > bb) bb = kk;
                        }
                    }
                } else {              // rebuild from CSR counts + slot-column overlays
                    for (int jb = tl * 4; jb < N; jb += 1024) {
                        float4 c4 = *reinterpret_cast<const float4*>(sc + jb);
                        float4 d4 = *reinterpret_cast<const float4*>(dinv + jb);
#pragma unroll
                        for (int m = 0; m < 4; ++m) {
                            int j = jb + m;
                            if (j <= ir) continue;
                            int sl2 = dslotL[j];
                            float v = (sl2 >= 0) ? colS[(size_t)sl2 * N + ir]
                                                 : -((di2 * (&c4.x)[m]) * (&d4.x)[m]);
                            u64 kk = packkey(fabsf(v), (unsigned)j);
                            if (kk > bb) bb = kk;
                        }
                    }
                }
            }
            for (int off = 32; off; off >>= 1) { u64 o = __shfl_down(bb, off, 64); if (o > bb) bb = o; }
            if ((t & 63) == 0) w16[t >> 6] = bb;
            __syncthreads();
            if (active && tl == 0) {
                u64 b = w16[g * 4];
                for (int w = 1; w < 4; ++w) if (w16[g * 4 + w] > b) b = w16[g * 4 + w];
                unsigned js = (~(unsigned)b) & 4095u;
                rmaxL[ir] = b;
                float v;
                if (slot >= 0) {
                    v = (js == (unsigned)k) ? sgSub[g][0] : (js == (unsigned)l) ? sgSub[g][1]
                        : rowS[(size_t)slot * N + js];
                } else {
                    int sl2 = dslotL[js];
                    v = (sl2 >= 0) ? colS[(size_t)sl2 * N + ir]
                                   : -((di2 * sc[js]) * dinv[js]);
                }
                rvalL[ir] = v;
            }
            __syncthreads();
        }
    }
    // epilogue: mirror state for tail kernels
    for (int i = t; i < N; i += 1024) {
        diag[i] = diagL[i];
        dslotG[i] = (int)dslotL[i];
    }
    if (t < S_ns) slistG[t] = slistL[t];
    if (t == 0) *nslotsG = S_ns;
}

// ---------- tail ----------
__global__ void __launch_bounds__(1024) spectral_k(
        const float* __restrict__ diag, const float* __restrict__ y,
        const float2* __restrict__ hcT, const float4* __restrict__ rwT,
        const float4* __restrict__ iwT, float* __restrict__ z) {
    int o = threadIdx.x & 63;
    int nl = threadIdx.x >> 6;
    int n = blockIdx.x * 16 + nl;
    __shared__ float saux[16][CIN];
    saux[nl][o] = y[n * CIN + o];
    __syncthreads();
    float wn = diag[n];
    const float C2 = -0.41614683654714241f;   // cos(2.0)
    const float S2 = 0.90929742682568170f;    // sin(2.0)
    float acc = 0.0f;
    for (int i = 0; i < CIN; ++i) {
        float2 hc = hcT[i * 64 + o];
        float hw = hc.x * wn;
        float t2v = hw * hw;
        float inv = 1.0f / (t2v + 1.0f);
        float c1 = (t2v - 1.0f) * inv;
        float s1 = (2.0f * hw) * inv;
        if (!(hw > 1e-5f)) { c1 = C2; s1 = S2; }
        float4 rwv = rwT[i * 64 + o];
        float4 iwv = iwT[i * 64 + o];
        float g = hc.y;
        float cj = c1, sj = s1;
        g += rwv.x * cj - iwv.x * sj;
        float cn = cj * c1 - sj * s1; float sn = sj * c1 + cj * s1; cj = cn; sj = sn;
        g += rwv.y * cj - iwv.y * sj;
        cn = cj * c1 - sj * s1; sn = sj * c1 + cj * s1; cj = cn; sj = sn;
        g += rwv.z * cj - iwv.z * sj;
        cn = cj * c1 - sj * s1; sn = sj * c1 + cj * s1; cj = cn; sj = sn;
        g += rwv.w * cj - iwv.w * sj;
        acc += g * saux[nl][i];
    }
    z[(size_t)n * COUT + o] = acc;
}

// Fused finalrot + bias + store. Blocks 0..1023: non-pivot rows. Block 1024:
// sequential rotation chain on the <=20 pivot rows (disjoint), then store them.
__global__ void store_fused_k(
        float* __restrict__ z, const float* __restrict__ bias,
        const int* __restrict__ dslot, const int* __restrict__ slistG,
        const int* __restrict__ nslotsG,
        const int* __restrict__ rotk, const int* __restrict__ rotl,
        const float* __restrict__ rotc, const float* __restrict__ rotsv,
        float* __restrict__ out) {
    int t = threadIdx.x;
    if (blockIdx.x < 1024) {
        int idx = blockIdx.x * 256 + t;
        int row = idx >> 6;
        if (dslot[row] < 0) out[idx] = z[idx] + bias[idx & 63];
    } else if (t < 64) {
        for (int i = ITERS - 1; i >= 0; --i) {
            int k = rotk[i], l = rotl[i];
            float c = rotc[i], s = rotsv[i];
            float zk = z[k * COUT + t];
            float zl = z[l * COUT + t];
            z[k * COUT + t] = c * zk + s * zl;
            z[l * COUT + t] = -s * zk + c * zl;
        }
        int ns = *nslotsG;
        for (int d = 0; d < ns; ++d) {
            int r = slistG[d];
            out[r * COUT + t] = z[r * COUT + t] + bias[t];
        }
    }
}

extern "C" void kernel_launch(void* const* d_in, const int* in_sizes, int n_in,
                              void* d_out, int out_size, void* d_ws, size_t ws_size,
                              hipStream_t stream) {
    const float* x   = (const float*)d_in[0];
    const int*   ei  = (const int*)d_in[1];
    const float* rw  = (const float*)d_in[2];
    const float* iw  = (const float*)d_in[3];
    const float* hh  = (const float*)d_in[4];
    const float* cw  = (const float*)d_in[5];
    const float* bias= (const float*)d_in[6];
    float* out = (float*)d_out;

    // Workspace carve (~7.5 MB)
    float* rowS = (float*)d_ws;                 // MAXS*N
    float* colS = rowS + (size_t)MAXS * N;      // MAXS*N
    float* y    = colS + (size_t)MAXS * N;      // N*CIN
    float* z    = y + N * CIN;                  // N*COUT
    float2* hcT = (float2*)(z + N * COUT);      // 4096 float2
    float4* rwT = (float4*)(hcT + 4096);        // 4096 float4
    float4* iwT = rwT + 4096;                   // 4096 float4
    float* dinv = (float*)(iwT + 4096);         // 4096
    float* diag = dinv + N;                     // 4096
    float* rowval = diag + N;                   // 4096
    u64* rowmax = (u64*)(rowval + N);           // 4096 u64
    int* rowptr = (int*)(rowmax + N);           // 4100
    int* fill   = rowptr + 4100;                // 4096
    int* deg    = fill + N;                     // 4096
    int* slist  = deg + N;                      // 64
    int* nslots = slist + 64;                   // 4
    int* dslot  = nslots + 4;                   // 4096
    int* rotk   = dslot + N;                    // 16
    int* rotl   = rotk + 16;                    // 16
    float* rotc = (float*)(rotl + 16);          // 16
    float* rotsv= rotc + 16;                    // 16
    int* colidx = (int*)(rotsv + 16);           // 400000

    int E = in_sizes[1] / 2;                    // row half of edge_index
    int eb = (E + 255) / 256;

    init_k<<<16, 256, 0, stream>>>(deg, fill);
    edges1_k<<<eb, 256, 0, stream>>>(ei, deg, E);
    scan_k<<<1, 1024, 0, stream>>>(deg, rowptr, dinv);
    edges2_k<<<eb, 256, 0, stream>>>(ei, rowptr, fill, colidx, E);
    prepw_k<<<16, 256, 0, stream>>>(hh, cw, rw, iw, hcT, rwT, iwT);
    rowmax0_k<<<N, 256, 0, stream>>>(rowptr, colidx, dinv, x, y, diag, rowmax, rowval);

    jacobi_k<<<1, 1024, 0, stream>>>(rowptr, colidx, dinv, diag, rowmax, rowval,
                                     y, rowS, colS, dslot, slist, nslots,
                                     rotk, rotl, rotc, rotsv);

    spectral_k<<<N / 16, 1024, 0, stream>>>(diag, y, hcT, rwT, iwT, z);
    store_fused_k<<<1025, 256, 0, stream>>>(z, bias, dslot, slist, nslots,
                                            rotk, rotl, rotc, rotsv, out);
}

// Round 10
// 264.686 us; speedup vs baseline: 1.4505x; 1.0753x over previous
//
#include <hip/hip_runtime.h>
#include <hip/hip_bf16.h>

// Match numpy: no FMA contraction anywhere that feeds the Jacobi pivots.
#pragma clang fp contract(off)

#define N 4096
#define CIN 64
#define COUT 64
#define ITERS 10
#define MAXS 32
#define CANDMAX 384

typedef unsigned long long u64;

// pack (|value|, col j): bigger value wins; tie -> smaller j
__device__ __forceinline__ u64 packkey(float v, unsigned j) {
    return ((u64)__float_as_uint(v) << 32) | (u64)(~j);
}
// global pivot key: (valbits, row-major flat idx asc on ties) in 56 bits
__device__ __forceinline__ u64 gkey(unsigned vb, unsigned row, unsigned col) {
    unsigned flat = (row << 12) | col;
    return ((u64)vb << 24) | (u64)((~flat) & 0xFFFFFFu);
}

// ---------- setup ----------
__global__ void init_prep_k(int* __restrict__ deg, int* __restrict__ fill,
                            const float* __restrict__ hh, const float* __restrict__ cw,
                            const float* __restrict__ rw, const float* __restrict__ iw,
                            float2* __restrict__ hcT, float4* __restrict__ rwT,
                            float4* __restrict__ iwT) {
    int b = blockIdx.x;
    if (b < 16) {
        int i = b * 256 + threadIdx.x;
        deg[i] = 0; fill[i] = 0;
    } else {
        int idx = (b - 16) * 256 + threadIdx.x;   // 4096 = i*64+o
        int i = idx >> 6, o = idx & 63;
        int src = o * 64 + i;
        hcT[idx] = make_float2(hh[src], cw[src]);
        rwT[idx] = make_float4(rw[src * 4 + 0], rw[src * 4 + 1], rw[src * 4 + 2], rw[src * 4 + 3]);
        iwT[idx] = make_float4(iw[src * 4 + 0], iw[src * 4 + 1], iw[src * 4 + 2], iw[src * 4 + 3]);
    }
}

__global__ void edges1_k(const int* __restrict__ ei, int* __restrict__ deg, int E) {
    int e = blockIdx.x * 256 + threadIdx.x;
    if (e < E) atomicAdd(&deg[ei[e]], 1);
}

__global__ void __launch_bounds__(1024) scan_k(const int* __restrict__ deg,
                                               int* __restrict__ rowptr,
                                               float* __restrict__ dinv) {
    __shared__ int ps[1024];
    int t = threadIdx.x, b = t * 4;
    int d0 = deg[b], d1 = deg[b + 1], d2 = deg[b + 2], d3 = deg[b + 3];
    int local = d0 + d1 + d2 + d3;
    ps[t] = local;
    __syncthreads();
    for (int off = 1; off < 1024; off <<= 1) {
        int v = (t >= off) ? ps[t - off] : 0;
        __syncthreads();
        ps[t] += v;
        __syncthreads();
    }
    int excl = ps[t] - local;
    rowptr[b] = excl; rowptr[b + 1] = excl + d0;
    rowptr[b + 2] = excl + d0 + d1; rowptr[b + 3] = excl + d0 + d1 + d2;
    if (t == 1023) rowptr[4096] = ps[1023];
    dinv[b]     = d0 > 0 ? 1.0f / sqrtf((float)d0) : 0.0f;
    dinv[b + 1] = d1 > 0 ? 1.0f / sqrtf((float)d1) : 0.0f;
    dinv[b + 2] = d2 > 0 ? 1.0f / sqrtf((float)d2) : 0.0f;
    dinv[b + 3] = d3 > 0 ? 1.0f / sqrtf((float)d3) : 0.0f;
}

__global__ void edges2_k(const int* __restrict__ ei, const int* __restrict__ rowptr,
                         int* __restrict__ fill, int* __restrict__ colidx, int E) {
    int e = blockIdx.x * 256 + threadIdx.x;
    if (e < E) {
        int r = ei[e], c = ei[E + e];
        int pos = rowptr[r] + atomicAdd(&fill[r], 1);
        colidx[pos] = c;
    }
}

// Sparse per-row top-24 (distinct columns, sorted desc by (val, -col)), diag, y=x.
// One 64-thread block per row; touches only CSR entries (no dense zero/scan).
__global__ void __launch_bounds__(64) rowmax0_k(
        const int* __restrict__ rowptr, const int* __restrict__ colidx,
        const float* __restrict__ dinv, const float* __restrict__ x,
        float* __restrict__ y, float* __restrict__ diag, u64* __restrict__ top24T) {
    const int i = blockIdx.x, t = threadIdx.x;
    __shared__ float row[N];        // touched-sparse
    __shared__ u64 cand[CANDMAX];
    __shared__ int scnt;
    int rs = rowptr[i], re = rowptr[i + 1];
    if (t == 0) { scnt = 0; row[i] = 0.0f; }
    __syncthreads();
    for (int e = rs + t; e < re; e += 64) { int c2 = colidx[e]; if (c2 >= i) row[c2] = 0.0f; }
    __syncthreads();
    for (int e = rs + t; e < re; e += 64) { int c2 = colidx[e]; if (c2 >= i) atomicAdd(&row[c2], 1.0f); }
    __syncthreads();
    float di = dinv[i];
    for (int e = rs + t; e < re; e += 64) {
        int c2 = colidx[e];
        if (c2 > i) {
            float v = -((di * row[c2]) * dinv[c2]);
            int idx = atomicAdd(&scnt, 1);
            if (idx < CANDMAX) cand[idx] = packkey(fabsf(v), (unsigned)c2);
        }
    }
    __syncthreads();
    int L = scnt < CANDMAX ? scnt : CANDMAX;
    for (int r = 0; r < 24; ++r) {
        u64 best = 0ull;
        for (int idx = t; idx < L; idx += 64) { u64 cc = cand[idx]; if (cc > best) best = cc; }
        for (int off = 32; off; off >>= 1) { u64 o = __shfl_xor(best, off, 64); if (o > best) best = o; }
        if (t == 0) top24T[(size_t)r * N + i] = best;
        for (int idx = t; idx < L; idx += 64) { if (cand[idx] == best) cand[idx] = 0ull; }
        __syncthreads();
    }
    if (t == 0) diag[i] = 1.0f - ((di * row[i]) * di);
    y[i * CIN + t] = x[i * CIN + t];
}

// ---------- persistent single-block Jacobi ----------
__global__ void __launch_bounds__(1024) jacobi_k(
        const int* __restrict__ rowptr, const int* __restrict__ colidx,
        const float* __restrict__ dinv,
        float* __restrict__ diag, const u64* __restrict__ top24T, float* __restrict__ y,
        float* __restrict__ rowS, float* __restrict__ colS,
        int* __restrict__ dslotG, int* __restrict__ slistG, int* __restrict__ nslotsG,
        int* __restrict__ rotk, int* __restrict__ rotl,
        float* __restrict__ rotc, float* __restrict__ rotsv) {
    __shared__ float cntK[N], cntL[N];     // 32 KB: counts in, new col-k/l values out
    __shared__ u64 rmaxL[N];               // 32 KB, packkey format
    __shared__ float rvalL[N];             // 16 KB (signed value at row argmax)
    __shared__ float diagL[N];             // 16 KB
    __shared__ short dslotL[N];            // 8 KB
    __shared__ u64 rmaxSlot[MAXS];         // slot-row keys, gkey format
    __shared__ u64 w16[16], w16b[16];
    __shared__ float ovRowK[MAXS], ovRowL[MAXS], ovColK[MAXS], ovColL[MAXS];
    __shared__ int slistL[MAXS];
    __shared__ unsigned short sdirty[64];
    __shared__ int S_k, S_l, S_slotk, S_slotl, S_oldk, S_oldl, S_nold, S_ns, S_snd;
    __shared__ float S_c, S_s, S_a2kk, S_a2ll;
    __shared__ u64 S_pivot;
    const int t = threadIdx.x;

    // prologue: init LDS state + first pivot reduce
    u64 mb0 = 0ull;
    for (int i = t; i < N; i += 1024) {
        u64 kk = top24T[i];                // c=0 plane = per-row initial max
        rmaxL[i] = kk;
        rvalL[i] = -__uint_as_float((unsigned)(kk >> 32));
        diagL[i] = diag[i];
        dslotL[i] = -1;
        unsigned col = (~(unsigned)kk) & 4095u;
        u64 gk = gkey((unsigned)(kk >> 32), (unsigned)i, col);
        if (gk > mb0) mb0 = gk;
    }
    if (t == 0) S_ns = 0;
    for (int off = 32; off; off >>= 1) { u64 o = __shfl_down(mb0, off, 64); if (o > mb0) mb0 = o; }
    if ((t & 63) == 0) w16[t >> 6] = mb0;
    __syncthreads();
    if (t == 0) { u64 b = w16[0]; for (int w = 1; w < 16; ++w) if (w16[w] > b) b = w16[w]; S_pivot = b; }
    __syncthreads();

    for (int it = 0; it < ITERS; ++it) {
        // ---- B1: decode pivot, rotation params, 2x2, slot bookkeeping ----
        if (t == 0) {
            unsigned flat = (~(unsigned)S_pivot) & 0xFFFFFFu;
            int k = (int)(flat >> 12), l = (int)(flat & 4095u);
            float akl = rvalL[k];
            float akk = diagL[k], all_ = diagL[l];
            float aDiff = all_ - akk;
            float akl_safe = (akl == 0.0f) ? 1.0f : akl;
            float aDiff_safe = (aDiff == 0.0f) ? 1.0f : aDiff;
            float phi = aDiff / (2.0f * akl_safe);
            float t2 = 1.0f / (fabsf(phi) + sqrtf(phi * phi + 1.0f));
            t2 = (phi < 0.0f) ? -t2 : t2;
            float t1 = akl / aDiff_safe;
            float tt = (fabsf(akl) < fabsf(aDiff) * 1e-36f) ? t1 : t2;
            float cv = 1.0f / sqrtf(tt * tt + 1.0f);
            float sv = tt * cv;
            rotk[it] = k; rotl[it] = l; rotc[it] = cv; rotsv[it] = sv;
            float a1kk = cv * akk - sv * akl;
            float a1kl = sv * akk + cv * akl;
            float a1lk = cv * akl - sv * all_;
            float a1ll = sv * akl + cv * all_;
            S_a2kk = cv * a1kk - sv * a1lk;
            S_a2ll = sv * a1kl + cv * a1ll;
            diagL[k] = S_a2kk; diagL[l] = S_a2ll;
            int ns = S_ns;
            S_nold = ns;
            int ok = dslotL[k]; S_oldk = ok;
            int sk2 = ok; if (ok < 0) { sk2 = ns; slistL[ns] = k; dslotL[k] = (short)ns; ns++; }
            int ol = dslotL[l]; S_oldl = ol;
            int sl3 = ol; if (ol < 0) { sl3 = ns; slistL[ns] = l; dslotL[l] = (short)ns; ns++; }
            S_ns = ns;
            S_k = k; S_l = l; S_slotk = sk2; S_slotl = sl3; S_c = cv; S_s = sv;
            S_snd = 0;
        }
        __syncthreads();
        const int k = S_k, l = S_l, slotk = S_slotk, slotl = S_slotl;
        const int oldk = S_oldk, oldl = S_oldl, nold = S_nold, ns = S_ns;
        const float c = S_c, s = S_s;
        const float a2kk = S_a2kk, a2ll = S_a2ll;
        const bool freshK = (oldk < 0), freshL = (oldl < 0);
        const float dk = dinv[k], dl = dinv[l];
        // ---- B2: y rot, overlay preloads, zero counts ----
        if (t < CIN) {
            float yk = y[k * CIN + t], yl = y[l * CIN + t];
            y[k * CIN + t] = c * yk - s * yl;
            y[l * CIN + t] = s * yk + c * yl;
        }
        if (t >= 64 && t < 64 + nold) {
            int sl2 = t - 64;
            if (freshK) { ovRowK[sl2] = colS[(size_t)sl2 * N + k]; ovColK[sl2] = rowS[(size_t)sl2 * N + k]; }
            if (freshL) { ovRowL[sl2] = colS[(size_t)sl2 * N + l]; ovColL[sl2] = rowS[(size_t)sl2 * N + l]; }
        }
        if (freshK) for (int j = t; j < N; j += 1024) cntK[j] = 0.0f;
        if (freshL) for (int j = t; j < N; j += 1024) cntL[j] = 0.0f;
        __syncthreads();
        // ---- B3: scatter counts for fresh pivots ----
        if (freshK || freshL) {
            if (freshK) for (int e = rowptr[k] + t; e < rowptr[k + 1]; e += 1024) atomicAdd(&cntK[colidx[e]], 1.0f);
            if (freshL) for (int e = rowptr[l] + t; e < rowptr[l + 1]; e += 1024) atomicAdd(&cntL[colidx[e]], 1.0f);
            __syncthreads();
        }
        // ---- (a): build + overlay + rotate + store; stash nck/ncl; bk/bl ----
        u64 bk = packkey(0.0f, 4095u), bl = packkey(0.0f, 4095u);
        {
            const int j0 = t * 4;
            float4 dj4 = *reinterpret_cast<const float4*>(dinv + j0);
            float4 bK4, bL4, cK4, cL4;
            if (freshK) {
                float4 cnt = *reinterpret_cast<const float4*>(cntK + j0);
#pragma unroll
                for (int m = 0; m < 4; ++m) {
                    float cn = (&cnt.x)[m], dj = (&dj4.x)[m];
                    (&bK4.x)[m] = -((dk * cn) * dj);
                    (&cK4.x)[m] = -((dj * cn) * dk);
                }
            } else {
                bK4 = *reinterpret_cast<const float4*>(rowS + (size_t)oldk * N + j0);
                cK4 = *reinterpret_cast<const float4*>(colS + (size_t)oldk * N + j0);
            }
            if (freshL) {
                float4 cnt = *reinterpret_cast<const float4*>(cntL + j0);
#pragma unroll
                for (int m = 0; m < 4; ++m) {
                    float cn = (&cnt.x)[m], dj = (&dj4.x)[m];
                    (&bL4.x)[m] = -((dl * cn) * dj);
                    (&cL4.x)[m] = -((dj * cn) * dl);
                }
            } else {
                bL4 = *reinterpret_cast<const float4*>(rowS + (size_t)oldl * N + j0);
                cL4 = *reinterpret_cast<const float4*>(colS + (size_t)oldl * N + j0);
            }
            float4 nrK4, nrL4, ncK4, ncL4;
#pragma unroll
            for (int m = 0; m < 4; ++m) {
                int j = j0 + m;
                float bK = (&bK4.x)[m], bL = (&bL4.x)[m];
                float cK = (&cK4.x)[m], cL = (&cL4.x)[m];
                float nrk, nrl, nck, ncl;
                if (j == k)      { nrk = a2kk; nrl = 0.0f; nck = a2kk; ncl = 0.0f; }
                else if (j == l) { nrk = 0.0f; nrl = a2ll; nck = 0.0f; ncl = a2ll; }
                else {
                    int sl2 = dslotL[j];
                    if (sl2 >= 0 && sl2 < nold) {
                        if (freshK) { bK = ovRowK[sl2]; cK = ovColK[sl2]; }
                        if (freshL) { bL = ovRowL[sl2]; cL = ovColL[sl2]; }
                    }
                    nrk = c * bK - s * bL; nrl = s * bK + c * bL;
                    nck = c * cK - s * cL; ncl = s * cK + c * cL;
                }
                (&nrK4.x)[m] = nrk; (&nrL4.x)[m] = nrl;
                (&ncK4.x)[m] = nck; (&ncL4.x)[m] = ncl;
                if (j > k) { u64 kk = packkey(fabsf(nrk), (unsigned)j); if (kk > bk) bk = kk; }
                if (j > l) { u64 kk = packkey(fabsf(nrl), (unsigned)j); if (kk > bl) bl = kk; }
            }
            *reinterpret_cast<float4*>(rowS + (size_t)slotk * N + j0) = nrK4;
            *reinterpret_cast<float4*>(rowS + (size_t)slotl * N + j0) = nrL4;
            *reinterpret_cast<float4*>(colS + (size_t)slotk * N + j0) = ncK4;
            *reinterpret_cast<float4*>(colS + (size_t)slotl * N + j0) = ncL4;
            *reinterpret_cast<float4*>(cntK + j0) = ncK4;   // stash for merge
            *reinterpret_cast<float4*>(cntL + j0) = ncL4;
        }
        for (int off = 32; off; off >>= 1) {
            u64 o = __shfl_down(bk, off, 64); if (o > bk) bk = o;
            u64 o2 = __shfl_down(bl, off, 64); if (o2 > bl) bl = o2;
        }
        if ((t & 63) == 0) { w16[t >> 6] = bk; w16b[t >> 6] = bl; }
        __syncthreads();
        // ---- (b)-phase: t0 finalize k/l; patch threads; coalesced merge ----
        if (t == 0) {
            u64 b1 = w16[0], b2 = w16b[0];
            for (int w = 1; w < 16; ++w) { if (w16[w] > b1) b1 = w16[w]; if (w16b[w] > b2) b2 = w16b[w]; }
            unsigned j1 = (~(unsigned)b1) & 4095u, j2 = (~(unsigned)b2) & 4095u;
            rvalL[k] = rowS[(size_t)slotk * N + j1];
            rvalL[l] = rowS[(size_t)slotl * N + j2];
            rmaxSlot[slotk] = gkey((unsigned)(b1 >> 32), (unsigned)k, j1);
            rmaxSlot[slotl] = gkey((unsigned)(b2 >> 32), (unsigned)l, j2);
        }
        if (t >= 64 && t < 64 + nold) {
            int sl2 = t - 64;
            int js = slistL[sl2];
            if (js != k && js != l) {
                float vkj = rowS[(size_t)slotk * N + js];   // new a_{k,js}
                float vlj = rowS[(size_t)slotl * N + js];   // new a_{l,js}
                float vjk = cntK[js];                        // new a_{js,k}
                float vjl = cntL[js];                        // new a_{js,l}
                colS[(size_t)sl2 * N + k] = vkj;
                colS[(size_t)sl2 * N + l] = vlj;
                rowS[(size_t)sl2 * N + k] = vjk;
                rowS[(size_t)sl2 * N + l] = vjl;
                u64 cached = rmaxSlot[sl2];
                unsigned cj = ((~(unsigned)cached) & 0xFFFFFFu) & 4095u;
                bool kc = (k > js), lc = (l > js);
                u64 ck2 = kc ? gkey(__float_as_uint(fabsf(vjk)), (unsigned)js, (unsigned)k) : 0ull;
                u64 cl2 = lc ? gkey(__float_as_uint(fabsf(vjl)), (unsigned)js, (unsigned)l) : 0ull;
                bool stale = false; u64 base = cached; bool useOld = true;
                if (kc && cj == (unsigned)k)      { if (ck2 < cached) stale = true; else { base = 0ull; useOld = false; } }
                else if (lc && cj == (unsigned)l) { if (cl2 < cached) stale = true; else { base = 0ull; useOld = false; } }
                if (!stale) {
                    if (kc || lc) {
                        u64 mm = base; float mv = useOld ? rvalL[js] : 0.0f;
                        if (ck2 > mm) { mm = ck2; mv = vjk; }
                        if (cl2 > mm) { mm = cl2; mv = vjl; }
                        rmaxSlot[sl2] = mm; rvalL[js] = mv;
                    }
                } else { int d2 = atomicAdd(&S_snd, 1); sdirty[d2] = (unsigned short)sl2; }
            }
        }
        u64 myBest = 0ull;
#pragma unroll
        for (int m = 0; m < 4; ++m) {
            int j = t + 1024 * m;
            if (j == k || j == l) continue;
            if (dslotL[j] >= 0) continue;            // slot rows via rmaxSlot
            float nck = cntK[j], ncl = cntL[j];
            u64 cached = rmaxL[j];
            unsigned cj = (~(unsigned)cached) & 4095u;
            bool kc = (k > j), lc = (l > j);
            u64 ck2 = kc ? packkey(fabsf(nck), (unsigned)k) : 0ull;
            u64 cl2 = lc ? packkey(fabsf(ncl), (unsigned)l) : 0ull;
            bool stale = false; u64 base = cached; bool useOld = true;
            if (kc && cj == (unsigned)k)      { if (ck2 < cached) stale = true; else { base = 0ull; useOld = false; } }
            else if (lc && cj == (unsigned)l) { if (cl2 < cached) stale = true; else { base = 0ull; useOld = false; } }
            if (!stale) {
                if (kc || lc) {
                    u64 mm = base; float mv = useOld ? rvalL[j] : 0.0f;
                    if (ck2 > mm) { mm = ck2; mv = nck; }
                    if (cl2 > mm) { mm = cl2; mv = ncl; }
                    rmaxL[j] = mm; rvalL[j] = mv;
                }
            } else {
                // fresh compute: static top-24 probe (early exit) + slots + k/l
                u64 bKey = 0ull; float bVal = 0.0f;
                for (int cc = 0; cc < 24; ++cc) {
                    u64 cand = top24T[(size_t)cc * N + j];
                    unsigned col = (~(unsigned)cand) & 4095u;
                    if (dslotL[col] < 0) {
                        bKey = cand;
                        bVal = -__uint_as_float((unsigned)(cand >> 32));
                        break;
                    }
                }
                for (int sl = 0; sl < ns; ++sl) {
                    if (sl == slotk || sl == slotl) continue;
                    int js = slistL[sl];
                    if (js > j) {
                        float v = colS[(size_t)sl * N + j];
                        u64 kk2 = packkey(fabsf(v), (unsigned)js);
                        if (kk2 > bKey) { bKey = kk2; bVal = v; }
                    }
                }
                if (kc && ck2 > bKey) { bKey = ck2; bVal = nck; }
                if (lc && cl2 > bKey) { bKey = cl2; bVal = ncl; }
                rmaxL[j] = bKey; rvalL[j] = bVal;
            }
            u64 fin = rmaxL[j];
            u64 gk = gkey((unsigned)(fin >> 32), (unsigned)j, (~(unsigned)fin) & 4095u);
            if (gk > myBest) myBest = gk;
        }
        __syncthreads();
        // ---- B6: dirty slot-row rescans (rare) ----
        const int nd = S_snd;
        for (int d = 0; d < nd; ++d) {
            int sl2 = sdirty[d];
            int ir = slistL[sl2];
            u64 bb = packkey(0.0f, 4095u);
            int jb = t * 4;
            float4 v4 = *reinterpret_cast<const float4*>(rowS + (size_t)sl2 * N + jb);
#pragma unroll
            for (int m = 0; m < 4; ++m) {
                int j = jb + m;
                if (j > ir) {
                    u64 kk = packkey(fabsf((&v4.x)[m]), (unsigned)j);
                    if (kk > bb) bb = kk;
                }
            }
            for (int off = 32; off; off >>= 1) { u64 o = __shfl_down(bb, off, 64); if (o > bb) bb = o; }
            if ((t & 63) == 0) w16[t >> 6] = bb;
            __syncthreads();
            if (t == 0) {
                u64 b = w16[0];
                for (int w = 1; w < 16; ++w) if (w16[w] > b) b = w16[w];
                unsigned js2 = (~(unsigned)b) & 4095u;
                rmaxSlot[sl2] = gkey((unsigned)(b >> 32), (unsigned)ir, js2);
                rvalL[ir] = rowS[(size_t)sl2 * N + js2];
            }
            __syncthreads();
        }
        // ---- B7: final pivot reduce (normal rows + slot rows incl. k,l) ----
        if (t < ns) { u64 o = rmaxSlot[t]; if (o > myBest) myBest = o; }
        for (int off = 32; off; off >>= 1) { u64 o = __shfl_down(myBest, off, 64); if (o > myBest) myBest = o; }
        if ((t & 63) == 0) w16[t >> 6] = myBest;
        __syncthreads();
        if (t == 0) { u64 b = w16[0]; for (int w = 1; w < 16; ++w) if (w16[w] > b) b = w16[w]; S_pivot = b; }
        __syncthreads();
    }
    // epilogue: mirror state for tail kernels
    for (int i = t; i < N; i += 1024) {
        diag[i] = diagL[i];
        dslotG[i] = (int)dslotL[i];
    }
    if (t < S_ns) slistG[t] = slistL[t];
    if (t == 0) *nslotsG = S_ns;
}

// ---------- tail ----------
__global__ void __launch_bounds__(1024) spectral_k(
        const float* __restrict__ diag, const float* __restrict__ y,
        const float2* __restrict__ hcT, const float4* __restrict__ rwT,
        const float4* __restrict__ iwT, float* __restrict__ z) {
    int o = threadIdx.x & 63;
    int nl = threadIdx.x >> 6;
    int n = blockIdx.x * 16 + nl;
    __shared__ float saux[16][CIN];
    saux[nl][o] = y[n * CIN + o];
    __syncthreads();
    float wn = diag[n];
    const float C2 = -0.41614683654714241f;   // cos(2.0)
    const float S2 = 0.90929742682568170f;    // sin(2.0)
    float acc = 0.0f;
    for (int i = 0; i < CIN; ++i) {
        float2 hc = hcT[i * 64 + o];
        float hw = hc.x * wn;
        float t2v = hw * hw;
        float inv = 1.0f / (t2v + 1.0f);
        float c1 = (t2v - 1.0f) * inv;
        float s1 = (2.0f * hw) * inv;
        if (!(hw > 1e-5f)) { c1 = C2; s1 = S2; }
        float4 rwv = rwT[i * 64 + o];
        float4 iwv = iwT[i * 64 + o];
        float g = hc.y;
        float cj = c1, sj = s1;
        g += rwv.x * cj - iwv.x * sj;
        float cn = cj * c1 - sj * s1; float sn = sj * c1 + cj * s1; cj = cn; sj = sn;
        g += rwv.y * cj - iwv.y * sj;
        cn = cj * c1 - sj * s1; sn = sj * c1 + cj * s1; cj = cn; sj = sn;
        g += rwv.z * cj - iwv.z * sj;
        cn = cj * c1 - sj * s1; sn = sj * c1 + cj * s1; cj = cn; sj = sn;
        g += rwv.w * cj - iwv.w * sj;
        acc += g * saux[nl][i];
    }
    z[(size_t)n * COUT + o] = acc;
}

// Fused finalrot + bias + store.
__global__ void store_fused_k(
        float* __restrict__ z, const float* __restrict__ bias,
        const int* __restrict__ dslot, const int* __restrict__ slistG,
        const int* __restrict__ nslotsG,
        const int* __restrict__ rotk, const int* __restrict__ rotl,
        const float* __restrict__ rotc, const float* __restrict__ rotsv,
        float* __restrict__ out) {
    int t = threadIdx.x;
    if (blockIdx.x < 1024) {
        int idx = blockIdx.x * 256 + t;
        int row = idx >> 6;
        if (dslot[row] < 0) out[idx] = z[idx] + bias[idx & 63];
    } else if (t < 64) {
        for (int i = ITERS - 1; i >= 0; --i) {
            int k = rotk[i], l = rotl[i];
            float c = rotc[i], s = rotsv[i];
            float zk = z[k * COUT + t];
            float zl = z[l * COUT + t];
            z[k * COUT + t] = c * zk + s * zl;
            z[l * COUT + t] = -s * zk + c * zl;
        }
        int ns = *nslotsG;
        for (int d = 0; d < ns; ++d) {
            int r = slistG[d];
            out[r * COUT + t] = z[r * COUT + t] + bias[t];
        }
    }
}

extern "C" void kernel_launch(void* const* d_in, const int* in_sizes, int n_in,
                              void* d_out, int out_size, void* d_ws, size_t ws_size,
                              hipStream_t stream) {
    const float* x   = (const float*)d_in[0];
    const int*   ei  = (const int*)d_in[1];
    const float* rw  = (const float*)d_in[2];
    const float* iw  = (const float*)d_in[3];
    const float* hh  = (const float*)d_in[4];
    const float* cw  = (const float*)d_in[5];
    const float* bias= (const float*)d_in[6];
    float* out = (float*)d_out;

    // Workspace carve (~6.1 MB)
    float* rowS = (float*)d_ws;                 // MAXS*N
    float* colS = rowS + (size_t)MAXS * N;      // MAXS*N
    float* y    = colS + (size_t)MAXS * N;      // N*CIN
    float* z    = y + N * CIN;                  // N*COUT
    float2* hcT = (float2*)(z + N * COUT);      // 4096 float2
    float4* rwT = (float4*)(hcT + 4096);        // 4096 float4
    float4* iwT = rwT + 4096;                   // 4096 float4
    float* dinv = (float*)(iwT + 4096);         // 4096
    float* diag = dinv + N;                     // 4096
    u64* top24T = (u64*)(diag + N);             // 24*N u64 (8-byte aligned)
    int* rowptr = (int*)(top24T + 24 * (size_t)N); // 4097 (+pad)
    int* fill   = rowptr + 4100;                // 4096
    int* deg    = fill + N;                     // 4096
    int* slist  = deg + N;                      // 64
    int* nslots = slist + 64;                   // 4
    int* dslot  = nslots + 4;                   // 4096
    int* rotk   = dslot + N;                    // 16
    int* rotl   = rotk + 16;                    // 16
    float* rotc = (float*)(rotl + 16);          // 16
    float* rotsv= rotc + 16;                    // 16
    int* colidx = (int*)(rotsv + 16);           // E

    int E = in_sizes[1] / 2;                    // row half of edge_index
    int eb = (E + 255) / 256;

    init_prep_k<<<32, 256, 0, stream>>>(deg, fill, hh, cw, rw, iw, hcT, rwT, iwT);
    edges1_k<<<eb, 256, 0, stream>>>(ei, deg, E);
    scan_k<<<1, 1024, 0, stream>>>(deg, rowptr, dinv);
    edges2_k<<<eb, 256, 0, stream>>>(ei, rowptr, fill, colidx, E);
    rowmax0_k<<<N, 64, 0, stream>>>(rowptr, colidx, dinv, x, y, diag, top24T);

    jacobi_k<<<1, 1024, 0, stream>>>(rowptr, colidx, dinv, diag, top24T,
                                     y, rowS, colS, dslot, slist, nslots,
                                     rotk, rotl, rotc, rotsv);

    spectral_k<<<N / 16, 1024, 0, stream>>>(diag, y, hcT, rwT, iwT, z);
    store_fused_k<<<1025, 256, 0, stream>>>(z, bias, dslot, slist, nslots,
                                            rotk, rotl, rotc, rotsv, out);
}